// Round 2
// baseline (19197.069 us; speedup 1.0000x reference)
//
#include <hip/hip_runtime.h>
#include <hip/hip_bf16.h>
#include <math.h>

#define S_LEN 4096
#define HID   2048
#define NH    8
#define NVH   16
#define DK    128
#define DV    128
#define KEY_DIM  (NH*DK)    // 1024
#define VAL_DIM  (NVH*DV)   // 2048
#define SCALE_Q  0.08838834764831845f  // 128^-0.5

typedef __attribute__((ext_vector_type(8))) short short8;   // 8 bf16
typedef __attribute__((ext_vector_type(4))) float f32x4;

// ---------------------------------------------------------------------------
// float -> bf16 cast, 4 elems/thread
// ---------------------------------------------------------------------------
__global__ __launch_bounds__(256) void cast_f2b(
    const float* __restrict__ in, __hip_bfloat16* __restrict__ out, int n) {
  int i = (blockIdx.x * 256 + threadIdx.x) * 4;
  if (i >= n) return;
  float4 v = *(const float4*)&in[i];
  union { __hip_bfloat16 b[4]; short4 s; } u;
  u.b[0] = __float2bfloat16(v.x); u.b[1] = __float2bfloat16(v.y);
  u.b[2] = __float2bfloat16(v.z); u.b[3] = __float2bfloat16(v.w);
  *(short4*)&out[i] = u.s;
}

// ---------------------------------------------------------------------------
// bf16 MFMA GEMM: C[M,N](fp32) = A[M,K] @ B[N,K]^T, bf16 inputs.
// M,N,K multiples of 128/128/32. 128x128 tile, 256 threads (4 waves, 2x2),
// BK=32, global_load_lds width 16, mfma_f32_16x16x32_bf16.
// ---------------------------------------------------------------------------
__device__ __forceinline__ void lds_load16(const __hip_bfloat16* g,
                                           __hip_bfloat16* l) {
  __builtin_amdgcn_global_load_lds(
      (const __attribute__((address_space(1))) unsigned int*)g,
      (__attribute__((address_space(3))) unsigned int*)l, 16, 0, 0);
}

__global__ __launch_bounds__(256) void gemm_bf16_bt(
    const __hip_bfloat16* __restrict__ A, const __hip_bfloat16* __restrict__ B,
    float* __restrict__ C, int M, int N, int K) {
  __shared__ __hip_bfloat16 sA[128 * 32];
  __shared__ __hip_bfloat16 sB[128 * 32];
  const int t = threadIdx.x;
  const int wave = t >> 6, lane = t & 63;
  const int bm = blockIdx.y, bn = blockIdx.x;
  const int wm = (wave & 1) * 64, wn = (wave >> 1) * 64;

  f32x4 zero = {0.f, 0.f, 0.f, 0.f};
  f32x4 acc[4][4];
  #pragma unroll
  for (int i = 0; i < 4; i++)
    #pragma unroll
    for (int j = 0; j < 4; j++) acc[i][j] = zero;

  // staging: linear 16B chunk li covers row li>>2, cols (li&3)*8 .. +8
  const int r0 = t >> 2,        c0 = (t & 3) * 8;
  const int r1 = (256 + t) >> 2, c1 = ((256 + t) & 3) * 8;
  const __hip_bfloat16* gA0 = A + (size_t)(bm * 128 + r0) * K + c0;
  const __hip_bfloat16* gA1 = A + (size_t)(bm * 128 + r1) * K + c1;
  const __hip_bfloat16* gB0 = B + (size_t)(bn * 128 + r0) * K + c0;
  const __hip_bfloat16* gB1 = B + (size_t)(bn * 128 + r1) * K + c1;
  __hip_bfloat16* lA0 = sA + (size_t)(wave * 64) * 8;        // wave-uniform
  __hip_bfloat16* lA1 = sA + (size_t)(256 + wave * 64) * 8;
  __hip_bfloat16* lB0 = sB + (size_t)(wave * 64) * 8;
  __hip_bfloat16* lB1 = sB + (size_t)(256 + wave * 64) * 8;

  const int fm = lane & 15, fk = (lane >> 4) * 8;

  for (int k0 = 0; k0 < K; k0 += 32) {
    lds_load16(gA0, lA0); lds_load16(gA1, lA1);
    lds_load16(gB0, lB0); lds_load16(gB1, lB1);
    gA0 += 32; gA1 += 32; gB0 += 32; gB1 += 32;
    __syncthreads();
    short8 a[4], b[4];
    #pragma unroll
    for (int i = 0; i < 4; i++)
      a[i] = *(const short8*)&sA[(size_t)(wm + i * 16 + fm) * 32 + fk];
    #pragma unroll
    for (int j = 0; j < 4; j++)
      b[j] = *(const short8*)&sB[(size_t)(wn + j * 16 + fm) * 32 + fk];
    #pragma unroll
    for (int i = 0; i < 4; i++)
      #pragma unroll
      for (int j = 0; j < 4; j++)
        acc[i][j] = __builtin_amdgcn_mfma_f32_16x16x32_bf16(a[i], b[j], acc[i][j], 0, 0, 0);
    __syncthreads();
  }
  // epilogue: C/D layout col=lane&15, row=(lane>>4)*4+reg  [m89-verified]
  #pragma unroll
  for (int i = 0; i < 4; i++) {
    #pragma unroll
    for (int j = 0; j < 4; j++) {
      int col = bn * 128 + wn + j * 16 + (lane & 15);
      int rw0 = bm * 128 + wm + i * 16 + (lane >> 4) * 4;
      #pragma unroll
      for (int r = 0; r < 4; r++)
        C[(size_t)(rw0 + r) * N + col] = acc[i][j][r];
    }
  }
}

// ---------------------------------------------------------------------------
// fp32 GEMM for the tiny N=16 projections (Wa, Wb)
// ---------------------------------------------------------------------------
__global__ __launch_bounds__(256) void gemm_bt(
    const float* __restrict__ A, const float* __restrict__ B,
    float* __restrict__ C, int M, int N, int K) {
  __shared__ float As[16][68];
  __shared__ float Bs[16][68];
  const int bm = blockIdx.y, bn = blockIdx.x;
  const int t = threadIdx.x;
  const int tx = t & 15, ty = t >> 4;
  const int lrow = t >> 2;
  const int lk0  = (t & 3) * 4;
  const int arow = bm * 64 + lrow;
  const int brow = bn * 64 + lrow;
  const bool bvalid = brow < N;

  float acc[4][4];
  #pragma unroll
  for (int i = 0; i < 4; i++)
    #pragma unroll
    for (int j = 0; j < 4; j++) acc[i][j] = 0.f;

  for (int k0 = 0; k0 < K; k0 += 16) {
    float4 av = *(const float4*)&A[(size_t)arow * K + k0 + lk0];
    float4 bv = bvalid ? *(const float4*)&B[(size_t)brow * K + k0 + lk0]
                       : make_float4(0.f, 0.f, 0.f, 0.f);
    As[lk0+0][lrow] = av.x; As[lk0+1][lrow] = av.y;
    As[lk0+2][lrow] = av.z; As[lk0+3][lrow] = av.w;
    Bs[lk0+0][lrow] = bv.x; Bs[lk0+1][lrow] = bv.y;
    Bs[lk0+2][lrow] = bv.z; Bs[lk0+3][lrow] = bv.w;
    __syncthreads();
    #pragma unroll
    for (int kk = 0; kk < 16; kk++) {
      float4 a = *(const float4*)&As[kk][ty * 4];
      float4 b = *(const float4*)&Bs[kk][tx * 4];
      float ar[4] = {a.x, a.y, a.z, a.w};
      float br[4] = {b.x, b.y, b.z, b.w};
      #pragma unroll
      for (int i = 0; i < 4; i++)
        #pragma unroll
        for (int j = 0; j < 4; j++) acc[i][j] += ar[i] * br[j];
    }
    __syncthreads();
  }
  #pragma unroll
  for (int i = 0; i < 4; i++) {
    int r = bm * 64 + ty * 4 + i;
    #pragma unroll
    for (int j = 0; j < 4; j++) {
      int c = bn * 64 + tx * 4 + j;
      if (c < N) C[(size_t)r * N + c] = acc[i][j];
    }
  }
}

// ---------------------------------------------------------------------------
// Causal depthwise conv (K=4) + SiLU + per-head l2norm (+scale) for q/k.
// ---------------------------------------------------------------------------
__global__ __launch_bounds__(128) void conv_qk_kernel(
    const float* __restrict__ pre, const float* __restrict__ cw,
    float* __restrict__ out, float scale) {
  const int s = blockIdx.x, h = blockIdx.y, t = threadIdx.x;
  const int c = h * 128 + t;
  const float4 w = *(const float4*)&cw[c * 4];
  float y = pre[(size_t)s * KEY_DIM + c] * w.w;
  if (s >= 1) y += pre[(size_t)(s-1) * KEY_DIM + c] * w.z;
  if (s >= 2) y += pre[(size_t)(s-2) * KEY_DIM + c] * w.y;
  if (s >= 3) y += pre[(size_t)(s-3) * KEY_DIM + c] * w.x;
  float v = y / (1.f + expf(-y));   // silu
  float ss = v * v;
  #pragma unroll
  for (int off = 1; off < 64; off <<= 1) ss += __shfl_xor(ss, off, 64);
  __shared__ float red[2];
  if ((t & 63) == 0) red[t >> 6] = ss;
  __syncthreads();
  float inv = scale / sqrtf(red[0] + red[1] + 1e-6f);
  out[((size_t)s * NH + h) * 128 + t] = v * inv;
}

// ---------------------------------------------------------------------------
// Causal depthwise conv + SiLU for v.
// ---------------------------------------------------------------------------
__global__ __launch_bounds__(256) void conv_v_kernel(
    const float* __restrict__ pre, const float* __restrict__ cw,
    float* __restrict__ out) {
  const int id = blockIdx.x * 256 + threadIdx.x;
  const int s = id >> 11, c = id & 2047;
  const float4 w = *(const float4*)&cw[c * 4];
  float y = pre[id] * w.w;
  if (s >= 1) y += pre[id - VAL_DIM]     * w.z;
  if (s >= 2) y += pre[id - 2*VAL_DIM]   * w.y;
  if (s >= 3) y += pre[id - 3*VAL_DIM]   * w.x;
  out[id] = y / (1.f + expf(-y));
}

// ---------------------------------------------------------------------------
// eg = exp(-exp(A_log)*softplus(a+dt_bias))  (decay factor), beta = sigmoid(b)
// ---------------------------------------------------------------------------
__global__ __launch_bounds__(256) void gb_kernel(
    const float* __restrict__ a_pre, const float* __restrict__ b_pre,
    const float* __restrict__ A_log, const float* __restrict__ dt_bias,
    float* __restrict__ egv, float* __restrict__ bv) {
  const int id = blockIdx.x * 256 + threadIdx.x;
  const int h = id & 15;
  float av = a_pre[id] + dt_bias[h];
  float sp = av > 20.f ? av : log1pf(expf(av));
  egv[id] = expf(-expf(A_log[h]) * sp);
  bv[id] = 1.f / (1.f + expf(-b_pre[id]));
}

// ---------------------------------------------------------------------------
// Sequential delta-rule scan, v2 (latency-tuned).
// 64 blocks = 16 heads x 4 col-blocks (32 cols). 8 lanes per col, CONSECUTIVE
// (reduction via xor 1/2/4 -> DPP, no LDS). exp(g) precomputed. Next-step
// operands prefetched from LDS. pred re-associated: p = eg*(k . S_old);
// S_new = eg*S + k*delta (fma); o = q . S_new (off critical path).
// ---------------------------------------------------------------------------
#define CH 32
__global__ __launch_bounds__(256) void scan_kernel(
    const float* __restrict__ qn, const float* __restrict__ kn,
    const float* __restrict__ vc, const float* __restrict__ egv,
    const float* __restrict__ bv, float* __restrict__ o) {
  const int head = blockIdx.x >> 2;
  const int cb   = blockIdx.x & 3;
  const int sh   = head >> 1;          // source q/k head (GVA=2)
  const int t = threadIdx.x;
  const int lane = t & 63, wave = t >> 6;
  const int kc = lane & 7;                  // k-chunk 0..7 (consecutive lanes)
  const int k0 = kc * 16;
  const int coll = wave * 8 + (lane >> 3);  // col 0..31 within block

  __shared__ float lk[CH][128];
  __shared__ float lq[CH][128];
  __shared__ float lv[CH][32];
  __shared__ float leg[CH];
  __shared__ float lb[CH];

  float S[16];
  #pragma unroll
  for (int i = 0; i < 16; i++) S[i] = 0.f;

  for (int s0 = 0; s0 < S_LEN; s0 += CH) {
    {
      const int c4 = t & 31, st0 = t >> 5;
      #pragma unroll
      for (int r = 0; r < 4; r++) {
        int ss = st0 + r * 8;
        size_t g = (size_t)(s0 + ss) * KEY_DIM + sh * 128 + c4 * 4;
        *(float4*)&lk[ss][c4 * 4] = *(const float4*)&kn[g];
        *(float4*)&lq[ss][c4 * 4] = *(const float4*)&qn[g];
      }
      const int c4v = t & 7, sv = t >> 3;
      *(float4*)&lv[sv][c4v * 4] =
          *(const float4*)&vc[(size_t)(s0 + sv) * VAL_DIM + head * 128 + cb * 32 + c4v * 4];
      if (t < CH)            leg[t]     = egv[(s0 + t) * NVH + head];
      else if (t < 2 * CH)   lb[t - CH] = bv[(s0 + t - CH) * NVH + head];
    }
    __syncthreads();

    float kk[16], qq[16], vv, eg, bb;
    // load step 0 (bank-staggered by kc to break 4-way conflicts)
    #pragma unroll
    for (int r = 0; r < 4; r++) {
      int rr = (r + kc) & 3;
      *(float4*)&kk[rr * 4] = *(const float4*)&lk[0][k0 + rr * 4];
      *(float4*)&qq[rr * 4] = *(const float4*)&lq[0][k0 + rr * 4];
    }
    vv = lv[0][coll]; eg = leg[0]; bb = lb[0];

    #pragma unroll
    for (int st = 0; st < CH; st++) {
      float kk2[16], qq2[16], vv2, eg2, bb2;
      if (st + 1 < CH) {
        #pragma unroll
        for (int r = 0; r < 4; r++) {
          int rr = (r + kc) & 3;
          *(float4*)&kk2[rr * 4] = *(const float4*)&lk[st + 1][k0 + rr * 4];
          *(float4*)&qq2[rr * 4] = *(const float4*)&lq[st + 1][k0 + rr * 4];
        }
        vv2 = lv[st + 1][coll]; eg2 = leg[st + 1]; bb2 = lb[st + 1];
      }
      // d = k . S_old  (tree)
      float d0 = 0.f, d1 = 0.f, d2 = 0.f, d3 = 0.f;
      #pragma unroll
      for (int i = 0; i < 4; i++) {
        d0 = fmaf(kk[i],      S[i],      d0);
        d1 = fmaf(kk[4 + i],  S[4 + i],  d1);
        d2 = fmaf(kk[8 + i],  S[8 + i],  d2);
        d3 = fmaf(kk[12 + i], S[12 + i], d3);
      }
      float d = (d0 + d1) + (d2 + d3);
      d += __shfl_xor(d, 1, 64);
      d += __shfl_xor(d, 2, 64);
      d += __shfl_xor(d, 4, 64);
      float delta = (vv - eg * d) * bb;
      // S = eg*S + k*delta ; o = q . S_new
      float o0 = 0.f, o1 = 0.f, o2 = 0.f, o3 = 0.f;
      #pragma unroll
      for (int i = 0; i < 4; i++) {
        S[i]      = fmaf(S[i],      eg, kk[i]      * delta);
        S[4 + i]  = fmaf(S[4 + i],  eg, kk[4 + i]  * delta);
        S[8 + i]  = fmaf(S[8 + i],  eg, kk[8 + i]  * delta);
        S[12 + i] = fmaf(S[12 + i], eg, kk[12 + i] * delta);
        o0 = fmaf(qq[i],      S[i],      o0);
        o1 = fmaf(qq[4 + i],  S[4 + i],  o1);
        o2 = fmaf(qq[8 + i],  S[8 + i],  o2);
        o3 = fmaf(qq[12 + i], S[12 + i], o3);
      }
      float oo = (o0 + o1) + (o2 + o3);
      oo += __shfl_xor(oo, 1, 64);
      oo += __shfl_xor(oo, 2, 64);
      oo += __shfl_xor(oo, 4, 64);
      if (kc == 0)
        o[(size_t)(s0 + st) * VAL_DIM + head * 128 + cb * 32 + coll] = oo;
      if (st + 1 < CH) {
        #pragma unroll
        for (int i = 0; i < 16; i++) { kk[i] = kk2[i]; qq[i] = qq2[i]; }
        vv = vv2; eg = eg2; bb = bb2;
      }
    }
    __syncthreads();
  }
}

// ---------------------------------------------------------------------------
// Gated RMSNorm -> bf16 output (feeds the bf16 Wo GEMM)
// ---------------------------------------------------------------------------
__global__ __launch_bounds__(128) void norm_kernel(
    const float* __restrict__ o, const float* __restrict__ gate,
    const float* __restrict__ w_norm, __hip_bfloat16* __restrict__ og) {
  const int s = blockIdx.x, h = blockIdx.y, t = threadIdx.x;
  const size_t idx = (size_t)s * VAL_DIM + h * 128 + t;
  float gt = gate[idx];
  float val = o[idx] * (gt / (1.f + expf(-gt)));
  float ss = val * val;
  #pragma unroll
  for (int off = 1; off < 64; off <<= 1) ss += __shfl_xor(ss, off, 64);
  __shared__ float red[2];
  if ((t & 63) == 0) red[t >> 6] = ss;
  __syncthreads();
  float ms = (red[0] + red[1]) * (1.f / 128.f);
  og[idx] = __float2bfloat16(val * (1.f / sqrtf(ms + 1e-6f)) * w_norm[t]);
}

// ---------------------------------------------------------------------------
extern "C" void kernel_launch(void* const* d_in, const int* in_sizes, int n_in,
                              void* d_out, int out_size, void* d_ws, size_t ws_size,
                              hipStream_t stream) {
  const float* x       = (const float*)d_in[0];
  const float* Wq      = (const float*)d_in[1];
  const float* Wk      = (const float*)d_in[2];
  const float* Wv      = (const float*)d_in[3];
  const float* Wa      = (const float*)d_in[4];
  const float* Wb      = (const float*)d_in[5];
  const float* Wg      = (const float*)d_in[6];
  const float* Wo      = (const float*)d_in[7];
  const float* conv_q  = (const float*)d_in[8];
  const float* conv_k  = (const float*)d_in[9];
  const float* conv_v  = (const float*)d_in[10];
  const float* A_log   = (const float*)d_in[11];
  const float* dt_bias = (const float*)d_in[12];
  const float* w_norm  = (const float*)d_in[13];
  float* out = (float*)d_out;

  float* W = (float*)d_ws;
  float* q_pre = W;                                   // 4096*1024
  float* k_pre = q_pre + (size_t)S_LEN * KEY_DIM;
  float* v_pre = k_pre + (size_t)S_LEN * KEY_DIM;     // 4096*2048
  float* qn    = v_pre + (size_t)S_LEN * VAL_DIM;
  float* kn    = qn    + (size_t)S_LEN * KEY_DIM;
  float* vcb   = kn    + (size_t)S_LEN * KEY_DIM;     // 4096*2048
  float* a_pre = vcb   + (size_t)S_LEN * VAL_DIM;
  float* b_pre = a_pre + (size_t)S_LEN * NVH;
  float* egv   = b_pre + (size_t)S_LEN * NVH;
  float* bvv   = egv   + (size_t)S_LEN * NVH;
  __hip_bfloat16* xb = (__hip_bfloat16*)(bvv + (size_t)S_LEN * NVH); // 4096*2048 bf16
  __hip_bfloat16* wb = xb + (size_t)S_LEN * HID;                     // up to 2048*2048 bf16
  // reuse: gate -> q_pre (fp32), o -> v_pre (fp32), ogb -> kn region (bf16)
  float* gate  = q_pre;
  float* obuf  = v_pre;
  __hip_bfloat16* ogb = (__hip_bfloat16*)kn;

  const int NCAST = 256 * 4;
  // 0) casts
  cast_f2b<<<(S_LEN*HID)/NCAST, 256, 0, stream>>>(x, xb, S_LEN*HID);

  // 1) projections (bf16 MFMA, weight buffer reused sequentially)
  cast_f2b<<<(KEY_DIM*HID)/NCAST, 256, 0, stream>>>(Wq, wb, KEY_DIM*HID);
  gemm_bf16_bt<<<dim3(KEY_DIM/128, S_LEN/128), 256, 0, stream>>>(xb, wb, q_pre, S_LEN, KEY_DIM, HID);
  cast_f2b<<<(KEY_DIM*HID)/NCAST, 256, 0, stream>>>(Wk, wb, KEY_DIM*HID);
  gemm_bf16_bt<<<dim3(KEY_DIM/128, S_LEN/128), 256, 0, stream>>>(xb, wb, k_pre, S_LEN, KEY_DIM, HID);
  cast_f2b<<<(VAL_DIM*HID)/NCAST, 256, 0, stream>>>(Wv, wb, VAL_DIM*HID);
  gemm_bf16_bt<<<dim3(VAL_DIM/128, S_LEN/128), 256, 0, stream>>>(xb, wb, v_pre, S_LEN, VAL_DIM, HID);
  gemm_bt<<<dim3(1, S_LEN/64), 256, 0, stream>>>(x, Wa, a_pre, S_LEN, NVH, HID);
  gemm_bt<<<dim3(1, S_LEN/64), 256, 0, stream>>>(x, Wb, b_pre, S_LEN, NVH, HID);

  // 2) conv + silu (+ l2norm for q/k), gating scalars
  conv_qk_kernel<<<dim3(S_LEN, NH), 128, 0, stream>>>(q_pre, conv_q, qn, SCALE_Q);
  conv_qk_kernel<<<dim3(S_LEN, NH), 128, 0, stream>>>(k_pre, conv_k, kn, 1.f);
  conv_v_kernel<<<(S_LEN*VAL_DIM)/256, 256, 0, stream>>>(v_pre, conv_v, vcb);
  gb_kernel<<<(S_LEN*NVH)/256, 256, 0, stream>>>(a_pre, b_pre, A_log, dt_bias, egv, bvv);

  // 3) gate projection into reclaimed q_pre
  cast_f2b<<<(VAL_DIM*HID)/NCAST, 256, 0, stream>>>(Wg, wb, VAL_DIM*HID);
  gemm_bf16_bt<<<dim3(VAL_DIM/128, S_LEN/128), 256, 0, stream>>>(xb, wb, gate, S_LEN, VAL_DIM, HID);

  // 4) sequential delta-rule scan (o -> reclaimed v_pre)
  scan_kernel<<<64, 256, 0, stream>>>(qn, kn, vcb, egv, bvv, obuf);

  // 5) gated RMSNorm -> bf16 (into reclaimed kn region)
  norm_kernel<<<dim3(S_LEN, NVH), 128, 0, stream>>>(obuf, gate, w_norm, ogb);

  // 6) output projection (bf16 MFMA)
  cast_f2b<<<(HID*VAL_DIM)/NCAST, 256, 0, stream>>>(Wo, wb, HID*VAL_DIM);
  gemm_bf16_bt<<<dim3(HID/128, S_LEN/128), 256, 0, stream>>>(ogb, wb, out, S_LEN, HID, VAL_DIM);
}

// Round 3
// 2861.270 us; speedup vs baseline: 6.7093x; 6.7093x over previous
//
#include <hip/hip_runtime.h>
#include <hip/hip_bf16.h>
#include <math.h>

#define S_LEN 4096
#define HID   2048
#define NH    8
#define NVH   16
#define DK    128
#define DV    128
#define KEY_DIM  (NH*DK)    // 1024
#define VAL_DIM  (NVH*DV)   // 2048
#define SCALE_Q  0.08838834764831845f  // 128^-0.5
#define CCH 64              // chunk length
#define NCH (S_LEN/CCH)     // 64 chunks

typedef __attribute__((ext_vector_type(8))) short short8;   // 8 bf16
typedef __attribute__((ext_vector_type(4))) float f32x4;

// ---------------------------------------------------------------------------
// float -> bf16 cast
// ---------------------------------------------------------------------------
__global__ __launch_bounds__(256) void cast_f2b(
    const float* __restrict__ in, __hip_bfloat16* __restrict__ out, int n) {
  int i = (blockIdx.x * 256 + threadIdx.x) * 4;
  if (i >= n) return;
  float4 v = *(const float4*)&in[i];
  union { __hip_bfloat16 b[4]; short4 s; } u;
  u.b[0] = __float2bfloat16(v.x); u.b[1] = __float2bfloat16(v.y);
  u.b[2] = __float2bfloat16(v.z); u.b[3] = __float2bfloat16(v.w);
  *(short4*)&out[i] = u.s;
}

// ---------------------------------------------------------------------------
// bf16 MFMA GEMM: C[M,N](fp32) = A[M,K] @ B[N,K]^T  (m97 structure)
// ---------------------------------------------------------------------------
__device__ __forceinline__ void lds_load16(const __hip_bfloat16* g,
                                           __hip_bfloat16* l) {
  __builtin_amdgcn_global_load_lds(
      (const __attribute__((address_space(1))) unsigned int*)g,
      (__attribute__((address_space(3))) unsigned int*)l, 16, 0, 0);
}

__global__ __launch_bounds__(256) void gemm_bf16_bt(
    const __hip_bfloat16* __restrict__ A, const __hip_bfloat16* __restrict__ B,
    float* __restrict__ C, int M, int N, int K) {
  __shared__ __hip_bfloat16 sA[128 * 32];
  __shared__ __hip_bfloat16 sB[128 * 32];
  const int t = threadIdx.x;
  const int wave = t >> 6, lane = t & 63;
  const int bm = blockIdx.y, bn = blockIdx.x;
  const int wm = (wave & 1) * 64, wn = (wave >> 1) * 64;

  f32x4 zero = {0.f, 0.f, 0.f, 0.f};
  f32x4 acc[4][4];
  #pragma unroll
  for (int i = 0; i < 4; i++)
    #pragma unroll
    for (int j = 0; j < 4; j++) acc[i][j] = zero;

  const int r0 = t >> 2,        c0 = (t & 3) * 8;
  const int r1 = (256 + t) >> 2, c1 = ((256 + t) & 3) * 8;
  const __hip_bfloat16* gA0 = A + (size_t)(bm * 128 + r0) * K + c0;
  const __hip_bfloat16* gA1 = A + (size_t)(bm * 128 + r1) * K + c1;
  const __hip_bfloat16* gB0 = B + (size_t)(bn * 128 + r0) * K + c0;
  const __hip_bfloat16* gB1 = B + (size_t)(bn * 128 + r1) * K + c1;
  __hip_bfloat16* lA0 = sA + (size_t)(wave * 64) * 8;
  __hip_bfloat16* lA1 = sA + (size_t)(256 + wave * 64) * 8;
  __hip_bfloat16* lB0 = sB + (size_t)(wave * 64) * 8;
  __hip_bfloat16* lB1 = sB + (size_t)(256 + wave * 64) * 8;

  const int fm = lane & 15, fk = (lane >> 4) * 8;

  for (int k0 = 0; k0 < K; k0 += 32) {
    lds_load16(gA0, lA0); lds_load16(gA1, lA1);
    lds_load16(gB0, lB0); lds_load16(gB1, lB1);
    gA0 += 32; gA1 += 32; gB0 += 32; gB1 += 32;
    __syncthreads();
    short8 a[4], b[4];
    #pragma unroll
    for (int i = 0; i < 4; i++)
      a[i] = *(const short8*)&sA[(size_t)(wm + i * 16 + fm) * 32 + fk];
    #pragma unroll
    for (int j = 0; j < 4; j++)
      b[j] = *(const short8*)&sB[(size_t)(wn + j * 16 + fm) * 32 + fk];
    #pragma unroll
    for (int i = 0; i < 4; i++)
      #pragma unroll
      for (int j = 0; j < 4; j++)
        acc[i][j] = __builtin_amdgcn_mfma_f32_16x16x32_bf16(a[i], b[j], acc[i][j], 0, 0, 0);
    __syncthreads();
  }
  #pragma unroll
  for (int i = 0; i < 4; i++) {
    #pragma unroll
    for (int j = 0; j < 4; j++) {
      int col = bn * 128 + wn + j * 16 + (lane & 15);
      int rw0 = bm * 128 + wm + i * 16 + (lane >> 4) * 4;
      #pragma unroll
      for (int r = 0; r < 4; r++)
        C[(size_t)(rw0 + r) * N + col] = acc[i][j][r];
    }
  }
}

// ---------------------------------------------------------------------------
// fp32 GEMM for the tiny N=16 projections (Wa, Wb)
// ---------------------------------------------------------------------------
__global__ __launch_bounds__(256) void gemm_bt(
    const float* __restrict__ A, const float* __restrict__ B,
    float* __restrict__ C, int M, int N, int K) {
  __shared__ float As[16][68];
  __shared__ float Bs[16][68];
  const int bm = blockIdx.y, bn = blockIdx.x;
  const int t = threadIdx.x;
  const int tx = t & 15, ty = t >> 4;
  const int lrow = t >> 2;
  const int lk0  = (t & 3) * 4;
  const int arow = bm * 64 + lrow;
  const int brow = bn * 64 + lrow;
  const bool bvalid = brow < N;

  float acc[4][4];
  #pragma unroll
  for (int i = 0; i < 4; i++)
    #pragma unroll
    for (int j = 0; j < 4; j++) acc[i][j] = 0.f;

  for (int k0 = 0; k0 < K; k0 += 16) {
    float4 av = *(const float4*)&A[(size_t)arow * K + k0 + lk0];
    float4 bv = bvalid ? *(const float4*)&B[(size_t)brow * K + k0 + lk0]
                       : make_float4(0.f, 0.f, 0.f, 0.f);
    As[lk0+0][lrow] = av.x; As[lk0+1][lrow] = av.y;
    As[lk0+2][lrow] = av.z; As[lk0+3][lrow] = av.w;
    Bs[lk0+0][lrow] = bv.x; Bs[lk0+1][lrow] = bv.y;
    Bs[lk0+2][lrow] = bv.z; Bs[lk0+3][lrow] = bv.w;
    __syncthreads();
    #pragma unroll
    for (int kk = 0; kk < 16; kk++) {
      float4 a = *(const float4*)&As[kk][ty * 4];
      float4 b = *(const float4*)&Bs[kk][tx * 4];
      float ar[4] = {a.x, a.y, a.z, a.w};
      float br[4] = {b.x, b.y, b.z, b.w};
      #pragma unroll
      for (int i = 0; i < 4; i++)
        #pragma unroll
        for (int j = 0; j < 4; j++) acc[i][j] += ar[i] * br[j];
    }
    __syncthreads();
  }
  #pragma unroll
  for (int i = 0; i < 4; i++) {
    int r = bm * 64 + ty * 4 + i;
    #pragma unroll
    for (int j = 0; j < 4; j++) {
      int c = bn * 64 + tx * 4 + j;
      if (c < N) C[(size_t)r * N + c] = acc[i][j];
    }
  }
}

// ---------------------------------------------------------------------------
// conv + SiLU + l2norm for q/k
// ---------------------------------------------------------------------------
__global__ __launch_bounds__(128) void conv_qk_kernel(
    const float* __restrict__ pre, const float* __restrict__ cw,
    float* __restrict__ out, float scale) {
  const int s = blockIdx.x, h = blockIdx.y, t = threadIdx.x;
  const int c = h * 128 + t;
  const float4 w = *(const float4*)&cw[c * 4];
  float y = pre[(size_t)s * KEY_DIM + c] * w.w;
  if (s >= 1) y += pre[(size_t)(s-1) * KEY_DIM + c] * w.z;
  if (s >= 2) y += pre[(size_t)(s-2) * KEY_DIM + c] * w.y;
  if (s >= 3) y += pre[(size_t)(s-3) * KEY_DIM + c] * w.x;
  float v = y / (1.f + expf(-y));
  float ss = v * v;
  #pragma unroll
  for (int off = 1; off < 64; off <<= 1) ss += __shfl_xor(ss, off, 64);
  __shared__ float red[2];
  if ((t & 63) == 0) red[t >> 6] = ss;
  __syncthreads();
  float inv = scale / sqrtf(red[0] + red[1] + 1e-6f);
  out[((size_t)s * NH + h) * 128 + t] = v * inv;
}

// ---------------------------------------------------------------------------
// conv + SiLU for v
// ---------------------------------------------------------------------------
__global__ __launch_bounds__(256) void conv_v_kernel(
    const float* __restrict__ pre, const float* __restrict__ cw,
    float* __restrict__ out) {
  const int id = blockIdx.x * 256 + threadIdx.x;
  const int s = id >> 11, c = id & 2047;
  const float4 w = *(const float4*)&cw[c * 4];
  float y = pre[id] * w.w;
  if (s >= 1) y += pre[id - VAL_DIM]     * w.z;
  if (s >= 2) y += pre[id - 2*VAL_DIM]   * w.y;
  if (s >= 3) y += pre[id - 3*VAL_DIM]   * w.x;
  out[id] = y / (1.f + expf(-y));
}

// ---------------------------------------------------------------------------
// gl = -exp(A_log)*softplus(a+dt_bias)  (LOG decay), beta = sigmoid(b)
// ---------------------------------------------------------------------------
__global__ __launch_bounds__(256) void gb_kernel(
    const float* __restrict__ a_pre, const float* __restrict__ b_pre,
    const float* __restrict__ A_log, const float* __restrict__ dt_bias,
    float* __restrict__ gl, float* __restrict__ bv) {
  const int id = blockIdx.x * 256 + threadIdx.x;
  const int h = id & 15;
  float av = a_pre[id] + dt_bias[h];
  float sp = av > 20.f ? av : log1pf(expf(av));
  gl[id] = -expf(A_log[h]) * sp;
  bv[id] = 1.f / (1.f + expf(-b_pre[id]));
}

// ---------------------------------------------------------------------------
// Phase A: per (chunk, head): build M, solve (I+M)W = B diag(e^G)K and
// (I+M)U = B V by fully-unrolled forward substitution. grid (NVH, NCH).
// ---------------------------------------------------------------------------
__global__ __launch_bounds__(256) void phaseA_kernel(
    const float* __restrict__ kn, const float* __restrict__ vc,
    const float* __restrict__ gl, const float* __restrict__ bvv,
    __hip_bfloat16* __restrict__ Wb, __hip_bfloat16* __restrict__ Ub,
    float* __restrict__ Gbuf) {
  const int h = blockIdx.x, c = blockIdx.y, sh = h >> 1;
  const int t = threadIdx.x;
  __shared__ float kch[64][132];
  __shared__ float vch[64][132];
  __shared__ float mm[64][65];
  __shared__ float Gs[64], bet[64], lamB[64];

  {
    const int r = t >> 2, c0 = (t & 3) * 32;
    const float* krow = kn + (size_t)(c*64 + r)*KEY_DIM + sh*128 + c0;
    const float* vrow = vc + (size_t)(c*64 + r)*VAL_DIM + h*128 + c0;
    #pragma unroll
    for (int i = 0; i < 8; i++) {
      *(float4*)&kch[r][c0 + 4*i] = *(const float4*)&krow[4*i];
      *(float4*)&vch[r][c0 + 4*i] = *(const float4*)&vrow[4*i];
    }
  }
  if (t < 64) {
    float g = gl[(size_t)(c*64 + t)*NVH + h];
    #pragma unroll
    for (int off = 1; off < 64; off <<= 1) {
      float p = __shfl_up(g, off, 64);
      if (t >= off) g += p;
    }
    Gs[t] = g;
    float b = bvv[(size_t)(c*64 + t)*NVH + h];
    bet[t] = b;
    lamB[t] = b * expf(g);
    Gbuf[((size_t)c*NVH + h)*64 + t] = g;
  }
  __syncthreads();

  // KK -> M  (thread computes a 4x4 block; d4 staggered by lb for banks)
  {
    const int jb = t >> 4, lb = t & 15;
    const int j0 = jb * 4, l0 = lb * 4;
    float acc[4][4] = {};
    for (int dd = 0; dd < 32; dd++) {
      const int d4 = ((dd + lb) & 31) * 4;
      float4 kj[4], kl[4];
      #pragma unroll
      for (int i = 0; i < 4; i++) {
        kj[i] = *(const float4*)&kch[j0 + i][d4];
        kl[i] = *(const float4*)&kch[l0 + i][d4];
      }
      #pragma unroll
      for (int i = 0; i < 4; i++)
        #pragma unroll
        for (int ii = 0; ii < 4; ii++)
          acc[i][ii] += kj[i].x*kl[ii].x + kj[i].y*kl[ii].y
                      + kj[i].z*kl[ii].z + kj[i].w*kl[ii].w;
    }
    #pragma unroll
    for (int i = 0; i < 4; i++)
      #pragma unroll
      for (int ii = 0; ii < 4; ii++) {
        int j = j0 + i, l = l0 + ii;
        mm[j][l] = (l < j) ? bet[j] * expf(Gs[j] - Gs[l]) * acc[i][ii] : 0.f;
      }
  }
  __syncthreads();

  // forward substitution: waves 0-1 -> W columns (dk), waves 2-3 -> U (dv)
  {
    const bool isW = t < 128;
    const int col = isW ? t : t - 128;
    float wcol[64];
    #pragma unroll
    for (int j = 0; j < 64; j++) {
      float s = isW ? lamB[j] * kch[j][col] : bet[j] * vch[j][col];
      #pragma unroll
      for (int l = 0; l < j; l++) s -= mm[j][l] * wcol[l];
      wcol[j] = s;
    }
    const size_t base = ((size_t)c*NVH + h) * 64 * 128;
    #pragma unroll
    for (int j = 0; j < 64; j++) {
      __hip_bfloat16 b = __float2bfloat16(wcol[j]);
      if (isW) Wb[base + j*128 + col] = b;
      else     Ub[base + j*128 + col] = b;
    }
  }
}

// ---------------------------------------------------------------------------
// Phase B: sequential over chunks, parallel over heads (grid 16).
// Per chunk: X = W S0, opart = (e^G q) S0, Delta = U - X (store),
// S = e^{G_C} S + K^T diag(e^{G_C-G_j}) Delta.   All matmuls MFMA.
// ---------------------------------------------------------------------------
__global__ __launch_bounds__(256, 1) void phaseB_kernel(
    const float* __restrict__ qn, const float* __restrict__ kn,
    const __hip_bfloat16* __restrict__ Wb, const __hip_bfloat16* __restrict__ Ub,
    const float* __restrict__ Gbuf,
    __hip_bfloat16* __restrict__ Db, float* __restrict__ obuf) {
  const int h = blockIdx.x, sh = h >> 1;
  const int t = threadIdx.x, lane = t & 63, w = t >> 6;
  const int fm = lane & 15, fq = lane >> 4;

  __shared__ __hip_bfloat16 S16T[128][136];  // S0 mirror, [vcol][dk]
  __shared__ __hip_bfloat16 kT[128][72];     // [dk][j]
  __shared__ __hip_bfloat16 q16[64][136];    // e^{G_j} q, [j][dk]
  __shared__ __hip_bfloat16 dT[128][72];     // e^{G_C-G_j} Delta, [vcol][j]
  __shared__ float Gs[64];

  f32x4 Sacc[2][8];
  #pragma unroll
  for (int ti = 0; ti < 2; ti++)
    #pragma unroll
    for (int tj = 0; tj < 8; tj++) Sacc[ti][tj] = (f32x4){0.f,0.f,0.f,0.f};
  for (int i = t; i < 128*136/2; i += 256) ((unsigned int*)S16T)[i] = 0;
  __syncthreads();

  for (int c = 0; c < NCH; c++) {
    const int cb = (c*NVH + h) * 64;
    if (t < 64) Gs[t] = Gbuf[(size_t)cb + t];
    __syncthreads();
    // stage q16 (scaled) and kT (transposed)
    {
      const int r = t >> 2, c0 = (t & 3) * 32;
      const float eg = expf(Gs[r]);
      const float* qrow = qn + (size_t)(c*64 + r)*KEY_DIM + sh*128 + c0;
      const float* krow = kn + (size_t)(c*64 + r)*KEY_DIM + sh*128 + c0;
      #pragma unroll
      for (int i = 0; i < 8; i++) {
        float4 qv = *(const float4*)&qrow[4*i];
        union { __hip_bfloat16 b[4]; unsigned long long u; } pq;
        pq.b[0] = __float2bfloat16(qv.x * eg);
        pq.b[1] = __float2bfloat16(qv.y * eg);
        pq.b[2] = __float2bfloat16(qv.z * eg);
        pq.b[3] = __float2bfloat16(qv.w * eg);
        *(unsigned long long*)&q16[r][c0 + 4*i] = pq.u;
        float4 kv = *(const float4*)&krow[4*i];
        kT[c0 + 4*i + 0][r] = __float2bfloat16(kv.x);
        kT[c0 + 4*i + 1][r] = __float2bfloat16(kv.y);
        kT[c0 + 4*i + 2][r] = __float2bfloat16(kv.z);
        kT[c0 + 4*i + 3][r] = __float2bfloat16(kv.w);
      }
    }
    __syncthreads();
    // (1)+(2): wave w handles result rows (chunk-j) 16w..16w+15
    f32x4 aX[8], aO[8];
    #pragma unroll
    for (int tj = 0; tj < 8; tj++) {
      aX[tj] = (f32x4){0.f,0.f,0.f,0.f};
      aO[tj] = (f32x4){0.f,0.f,0.f,0.f};
    }
    #pragma unroll
    for (int k0 = 0; k0 < 128; k0 += 32) {
      short8 aW = *(const short8*)&Wb[(size_t)(cb + 16*w + fm)*128 + k0 + fq*8];
      short8 aQ = *(const short8*)&q16[16*w + fm][k0 + fq*8];
      #pragma unroll
      for (int tj = 0; tj < 8; tj++) {
        short8 b = *(const short8*)&S16T[16*tj + fm][k0 + fq*8];
        aX[tj] = __builtin_amdgcn_mfma_f32_16x16x32_bf16(aW, b, aX[tj], 0, 0, 0);
        aO[tj] = __builtin_amdgcn_mfma_f32_16x16x32_bf16(aQ, b, aO[tj], 0, 0, 0);
      }
    }
    // Delta, opart stores, dT build
    const float gC = Gs[63];
    const int j0 = 16*w + fq*4;
    float er[4];
    #pragma unroll
    for (int r2 = 0; r2 < 4; r2++) er[r2] = expf(gC - Gs[j0 + r2]);
    #pragma unroll
    for (int tj = 0; tj < 8; tj++) {
      const int n = 16*tj + fm;
      union { __hip_bfloat16 b[4]; unsigned long long u; } pd;
      #pragma unroll
      for (int r2 = 0; r2 < 4; r2++) {
        const int j = j0 + r2;
        float u = __bfloat162float(Ub[(size_t)(cb + j)*128 + n]);
        float d = u - aX[tj][r2];
        Db[(size_t)(cb + j)*128 + n] = __float2bfloat16(d);
        pd.b[r2] = __float2bfloat16(d * er[r2]);
        obuf[((size_t)(c*64 + j)*NVH + h)*128 + n] = aO[tj][r2];
      }
      *(unsigned long long*)&dT[n][j0] = pd.u;
    }
    // decay S
    const float lamC = expf(gC);
    #pragma unroll
    for (int ti = 0; ti < 2; ti++)
      #pragma unroll
      for (int tj = 0; tj < 8; tj++)
        #pragma unroll
        for (int r2 = 0; r2 < 4; r2++) Sacc[ti][tj][r2] *= lamC;
    __syncthreads();
    // (3): S += K^T dT'   (wave w owns dk rows 32w..32w+31)
    #pragma unroll
    for (int ti = 0; ti < 2; ti++) {
      const int m0 = 32*w + 16*ti;
      #pragma unroll
      for (int kk0 = 0; kk0 < 64; kk0 += 32) {
        short8 aK = *(const short8*)&kT[m0 + fm][kk0 + fq*8];
        #pragma unroll
        for (int tj = 0; tj < 8; tj++) {
          short8 bD = *(const short8*)&dT[16*tj + fm][kk0 + fq*8];
          Sacc[ti][tj] = __builtin_amdgcn_mfma_f32_16x16x32_bf16(aK, bD, Sacc[ti][tj], 0, 0, 0);
        }
      }
    }
    // refresh bf16 mirror
    #pragma unroll
    for (int ti = 0; ti < 2; ti++) {
      const int dk0 = 32*w + 16*ti + fq*4;
      #pragma unroll
      for (int tj = 0; tj < 8; tj++) {
        const int n = 16*tj + fm;
        union { __hip_bfloat16 b[4]; unsigned long long u; } ps;
        #pragma unroll
        for (int r2 = 0; r2 < 4; r2++) ps.b[r2] = __float2bfloat16(Sacc[ti][tj][r2]);
        *(unsigned long long*)&S16T[n][dk0] = ps.u;
      }
    }
    __syncthreads();
  }
}

// ---------------------------------------------------------------------------
// Phase C: o += P Delta, P[j][l] = e^{G_j-G_l} (q_j.k_l), l<=j. grid (NVH,NCH)
// ---------------------------------------------------------------------------
__global__ __launch_bounds__(256) void phaseC_kernel(
    const float* __restrict__ qn, const float* __restrict__ kn,
    const float* __restrict__ Gbuf, const __hip_bfloat16* __restrict__ Db,
    float* __restrict__ obuf) {
  const int h = blockIdx.x, c = blockIdx.y, sh = h >> 1;
  const int t = threadIdx.x;
  __shared__ float qch[64][132];
  __shared__ float kch[64][132];
  __shared__ float PT[64][68];              // [l][j]
  __shared__ __hip_bfloat16 dch[64][136];   // [l][n]
  __shared__ float Gs[64];

  {
    const int r = t >> 2, c0 = (t & 3) * 32;
    const float* qrow = qn + (size_t)(c*64 + r)*KEY_DIM + sh*128 + c0;
    const float* krow = kn + (size_t)(c*64 + r)*KEY_DIM + sh*128 + c0;
    #pragma unroll
    for (int i = 0; i < 8; i++) {
      *(float4*)&qch[r][c0 + 4*i] = *(const float4*)&qrow[4*i];
      *(float4*)&kch[r][c0 + 4*i] = *(const float4*)&krow[4*i];
    }
    const __hip_bfloat16* drow = Db + ((size_t)c*NVH + h)*64*128 + (size_t)r*128 + c0;
    #pragma unroll
    for (int i = 0; i < 4; i++)
      *(short8*)&dch[r][c0 + 8*i] = *(const short8*)&drow[8*i];
  }
  if (t < 64) Gs[t] = Gbuf[((size_t)c*NVH + h)*64 + t];
  __syncthreads();

  // P = QK^T (decayed, causal-inclusive) -> PT
  {
    const int jb = t >> 4, lb = t & 15;
    const int j0 = jb * 4, l0 = lb * 4;
    float acc[4][4] = {};
    for (int dd = 0; dd < 32; dd++) {
      const int d4 = ((dd + lb) & 31) * 4;
      float4 qj[4], kl[4];
      #pragma unroll
      for (int i = 0; i < 4; i++) {
        qj[i] = *(const float4*)&qch[j0 + i][d4];
        kl[i] = *(const float4*)&kch[l0 + i][d4];
      }
      #pragma unroll
      for (int i = 0; i < 4; i++)
        #pragma unroll
        for (int ii = 0; ii < 4; ii++)
          acc[i][ii] += qj[i].x*kl[ii].x + qj[i].y*kl[ii].y
                      + qj[i].z*kl[ii].z + qj[i].w*kl[ii].w;
    }
    #pragma unroll
    for (int i = 0; i < 4; i++)
      #pragma unroll
      for (int ii = 0; ii < 4; ii++) {
        int j = j0 + i, l = l0 + ii;
        PT[l][j] = (l <= j) ? expf(Gs[j] - Gs[l]) * acc[i][ii] : 0.f;
      }
  }
  __syncthreads();

  // out[j][n] += sum_l PT[l][j] * dch[l][n]
  {
    const int j0 = (t >> 5) * 8;
    const int n0 = (t & 31) * 4;
    float acc2[8][4] = {};
    for (int l = 0; l < 64; l++) {
      float4 p0 = *(const float4*)&PT[l][j0];
      float4 p1 = *(const float4*)&PT[l][j0 + 4];
      float pj[8] = {p0.x,p0.y,p0.z,p0.w,p1.x,p1.y,p1.z,p1.w};
      float dv[4];
      #pragma unroll
      for (int ii = 0; ii < 4; ii++) dv[ii] = __bfloat162float(dch[l][n0 + ii]);
      #pragma unroll
      for (int i = 0; i < 8; i++)
        #pragma unroll
        for (int ii = 0; ii < 4; ii++)
          acc2[i][ii] += pj[i] * dv[ii];
    }
    #pragma unroll
    for (int i = 0; i < 8; i++) {
      float* orow = obuf + ((size_t)(c*64 + j0 + i)*NVH + h)*128 + n0;
      float4 o4 = *(const float4*)orow;
      o4.x += acc2[i][0]; o4.y += acc2[i][1];
      o4.z += acc2[i][2]; o4.w += acc2[i][3];
      *(float4*)orow = o4;
    }
  }
}

// ---------------------------------------------------------------------------
// Gated RMSNorm -> bf16
// ---------------------------------------------------------------------------
__global__ __launch_bounds__(128) void norm_kernel(
    const float* __restrict__ o, const float* __restrict__ gate,
    const float* __restrict__ w_norm, __hip_bfloat16* __restrict__ og) {
  const int s = blockIdx.x, h = blockIdx.y, t = threadIdx.x;
  const size_t idx = (size_t)s * VAL_DIM + h * 128 + t;
  float gt = gate[idx];
  float val = o[idx] * (gt / (1.f + expf(-gt)));
  float ss = val * val;
  #pragma unroll
  for (int off = 1; off < 64; off <<= 1) ss += __shfl_xor(ss, off, 64);
  __shared__ float red[2];
  if ((t & 63) == 0) red[t >> 6] = ss;
  __syncthreads();
  float ms = (red[0] + red[1]) * (1.f / 128.f);
  og[idx] = __float2bfloat16(val * (1.f / sqrtf(ms + 1e-6f)) * w_norm[t]);
}

// ---------------------------------------------------------------------------
extern "C" void kernel_launch(void* const* d_in, const int* in_sizes, int n_in,
                              void* d_out, int out_size, void* d_ws, size_t ws_size,
                              hipStream_t stream) {
  const float* x       = (const float*)d_in[0];
  const float* Wq      = (const float*)d_in[1];
  const float* Wk      = (const float*)d_in[2];
  const float* Wv      = (const float*)d_in[3];
  const float* Wa      = (const float*)d_in[4];
  const float* Wb_     = (const float*)d_in[5];
  const float* Wg      = (const float*)d_in[6];
  const float* Wo      = (const float*)d_in[7];
  const float* conv_q  = (const float*)d_in[8];
  const float* conv_k  = (const float*)d_in[9];
  const float* conv_v  = (const float*)d_in[10];
  const float* A_log   = (const float*)d_in[11];
  const float* dt_bias = (const float*)d_in[12];
  const float* w_norm  = (const float*)d_in[13];
  float* out = (float*)d_out;

  const size_t QK = (size_t)S_LEN * KEY_DIM;   // 4.19M
  const size_t SV = (size_t)S_LEN * VAL_DIM;   // 8.39M
  const size_t SM = (size_t)S_LEN * NVH;       // 65536

  float* W = (float*)d_ws;
  float* q_pre = W;
  float* k_pre = q_pre + QK;
  float* v_pre = k_pre + QK;       // SV floats; later: Ub (bf16) | Db (bf16)
  float* qn    = v_pre + SV;
  float* kn    = qn + QK;
  float* vcb   = kn + QK;          // SV floats; later: obuf
  float* a_pre = vcb + SV;
  float* b_pre = a_pre + SM;
  float* glb   = b_pre + SM;
  float* beta  = glb + SM;
  float* Gbuf  = beta + SM;        // NCH*NVH*64 = 65536
  __hip_bfloat16* xb = (__hip_bfloat16*)(Gbuf + SM);  // 8.39M bf16; later: Wb
  __hip_bfloat16* wb = xb + SV;                       // up to 4.19M bf16

  float* gate = q_pre;             // after convs
  float* obuf = vcb;               // after phase A
  __hip_bfloat16* ogb = (__hip_bfloat16*)kn;  // after phase C... norm out
  __hip_bfloat16* Wbb = xb;                   // after gate gemm
  __hip_bfloat16* Ub  = (__hip_bfloat16*)v_pre;
  __hip_bfloat16* Db  = (__hip_bfloat16*)(v_pre + SV/2);

  const int NC = 256 * 4;
  cast_f2b<<<(S_LEN*HID)/NC, 256, 0, stream>>>(x, xb, S_LEN*HID);

  cast_f2b<<<(KEY_DIM*HID)/NC, 256, 0, stream>>>(Wq, wb, KEY_DIM*HID);
  gemm_bf16_bt<<<dim3(KEY_DIM/128, S_LEN/128), 256, 0, stream>>>(xb, wb, q_pre, S_LEN, KEY_DIM, HID);
  cast_f2b<<<(KEY_DIM*HID)/NC, 256, 0, stream>>>(Wk, wb, KEY_DIM*HID);
  gemm_bf16_bt<<<dim3(KEY_DIM/128, S_LEN/128), 256, 0, stream>>>(xb, wb, k_pre, S_LEN, KEY_DIM, HID);
  cast_f2b<<<(VAL_DIM*HID)/NC, 256, 0, stream>>>(Wv, wb, VAL_DIM*HID);
  gemm_bf16_bt<<<dim3(VAL_DIM/128, S_LEN/128), 256, 0, stream>>>(xb, wb, v_pre, S_LEN, VAL_DIM, HID);
  gemm_bt<<<dim3(1, S_LEN/64), 256, 0, stream>>>(x, Wa, a_pre, S_LEN, NVH, HID);
  gemm_bt<<<dim3(1, S_LEN/64), 256, 0, stream>>>(x, Wb_, b_pre, S_LEN, NVH, HID);

  conv_qk_kernel<<<dim3(S_LEN, NH), 128, 0, stream>>>(q_pre, conv_q, qn, SCALE_Q);
  conv_qk_kernel<<<dim3(S_LEN, NH), 128, 0, stream>>>(k_pre, conv_k, kn, 1.f);
  conv_v_kernel<<<(S_LEN*VAL_DIM)/256, 256, 0, stream>>>(v_pre, conv_v, vcb);
  gb_kernel<<<(S_LEN*NVH)/256, 256, 0, stream>>>(a_pre, b_pre, A_log, dt_bias, glb, beta);

  cast_f2b<<<(VAL_DIM*HID)/NC, 256, 0, stream>>>(Wg, wb, VAL_DIM*HID);
  gemm_bf16_bt<<<dim3(VAL_DIM/128, S_LEN/128), 256, 0, stream>>>(xb, wb, gate, S_LEN, VAL_DIM, HID);

  // chunked delta-rule scan
  phaseA_kernel<<<dim3(NVH, NCH), 256, 0, stream>>>(kn, vcb, glb, beta, Wbb, Ub, Gbuf);
  phaseB_kernel<<<NVH, 256, 0, stream>>>(qn, kn, Wbb, Ub, Gbuf, Db, obuf);
  phaseC_kernel<<<dim3(NVH, NCH), 256, 0, stream>>>(qn, kn, Gbuf, Db, obuf);

  norm_kernel<<<dim3(S_LEN, NVH), 128, 0, stream>>>(obuf, gate, w_norm, ogb);

  cast_f2b<<<(HID*VAL_DIM)/NC, 256, 0, stream>>>(Wo, wb, HID*VAL_DIM);
  gemm_bf16_bt<<<dim3(HID/128, S_LEN/128), 256, 0, stream>>>(ogb, wb, out, S_LEN, HID, VAL_DIM);
}

// Round 4
// 1352.958 us; speedup vs baseline: 14.1890x; 2.1148x over previous
//
#include <hip/hip_runtime.h>
#include <hip/hip_bf16.h>
#include <math.h>

#define S_LEN 4096
#define HID   2048
#define NH    8
#define NVH   16
#define DK    128
#define DV    128
#define KEY_DIM  (NH*DK)    // 1024
#define VAL_DIM  (NVH*DV)   // 2048
#define SCALE_Q  0.08838834764831845f  // 128^-0.5
#define CCH 64              // chunk length
#define NCH (S_LEN/CCH)     // 64 chunks

typedef __attribute__((ext_vector_type(8))) short short8;   // 8 bf16
typedef __attribute__((ext_vector_type(4))) float f32x4;

// ---------------------------------------------------------------------------
// float -> bf16 cast
// ---------------------------------------------------------------------------
__global__ __launch_bounds__(256) void cast_f2b(
    const float* __restrict__ in, __hip_bfloat16* __restrict__ out, int n) {
  int i = (blockIdx.x * 256 + threadIdx.x) * 4;
  if (i >= n) return;
  float4 v = *(const float4*)&in[i];
  union { __hip_bfloat16 b[4]; short4 s; } u;
  u.b[0] = __float2bfloat16(v.x); u.b[1] = __float2bfloat16(v.y);
  u.b[2] = __float2bfloat16(v.z); u.b[3] = __float2bfloat16(v.w);
  *(short4*)&out[i] = u.s;
}

// ---------------------------------------------------------------------------
// bf16 MFMA GEMM: C[M,N](fp32) = A[M,K] @ B[N,K]^T  (m97 structure)
// ---------------------------------------------------------------------------
__device__ __forceinline__ void lds_load16(const __hip_bfloat16* g,
                                           __hip_bfloat16* l) {
  __builtin_amdgcn_global_load_lds(
      (const __attribute__((address_space(1))) unsigned int*)g,
      (__attribute__((address_space(3))) unsigned int*)l, 16, 0, 0);
}

__global__ __launch_bounds__(256) void gemm_bf16_bt(
    const __hip_bfloat16* __restrict__ A, const __hip_bfloat16* __restrict__ B,
    float* __restrict__ C, int M, int N, int K) {
  __shared__ __hip_bfloat16 sA[128 * 32];
  __shared__ __hip_bfloat16 sB[128 * 32];
  const int t = threadIdx.x;
  const int wave = t >> 6, lane = t & 63;
  const int bm = blockIdx.y, bn = blockIdx.x;
  const int wm = (wave & 1) * 64, wn = (wave >> 1) * 64;

  f32x4 zero = {0.f, 0.f, 0.f, 0.f};
  f32x4 acc[4][4];
  #pragma unroll
  for (int i = 0; i < 4; i++)
    #pragma unroll
    for (int j = 0; j < 4; j++) acc[i][j] = zero;

  const int r0 = t >> 2,        c0 = (t & 3) * 8;
  const int r1 = (256 + t) >> 2, c1 = ((256 + t) & 3) * 8;
  const __hip_bfloat16* gA0 = A + (size_t)(bm * 128 + r0) * K + c0;
  const __hip_bfloat16* gA1 = A + (size_t)(bm * 128 + r1) * K + c1;
  const __hip_bfloat16* gB0 = B + (size_t)(bn * 128 + r0) * K + c0;
  const __hip_bfloat16* gB1 = B + (size_t)(bn * 128 + r1) * K + c1;
  __hip_bfloat16* lA0 = sA + (size_t)(wave * 64) * 8;
  __hip_bfloat16* lA1 = sA + (size_t)(256 + wave * 64) * 8;
  __hip_bfloat16* lB0 = sB + (size_t)(wave * 64) * 8;
  __hip_bfloat16* lB1 = sB + (size_t)(256 + wave * 64) * 8;

  const int fm = lane & 15, fk = (lane >> 4) * 8;

  for (int k0 = 0; k0 < K; k0 += 32) {
    lds_load16(gA0, lA0); lds_load16(gA1, lA1);
    lds_load16(gB0, lB0); lds_load16(gB1, lB1);
    gA0 += 32; gA1 += 32; gB0 += 32; gB1 += 32;
    __syncthreads();
    short8 a[4], b[4];
    #pragma unroll
    for (int i = 0; i < 4; i++)
      a[i] = *(const short8*)&sA[(size_t)(wm + i * 16 + fm) * 32 + fk];
    #pragma unroll
    for (int j = 0; j < 4; j++)
      b[j] = *(const short8*)&sB[(size_t)(wn + j * 16 + fm) * 32 + fk];
    #pragma unroll
    for (int i = 0; i < 4; i++)
      #pragma unroll
      for (int j = 0; j < 4; j++)
        acc[i][j] = __builtin_amdgcn_mfma_f32_16x16x32_bf16(a[i], b[j], acc[i][j], 0, 0, 0);
    __syncthreads();
  }
  #pragma unroll
  for (int i = 0; i < 4; i++) {
    #pragma unroll
    for (int j = 0; j < 4; j++) {
      int col = bn * 128 + wn + j * 16 + (lane & 15);
      int rw0 = bm * 128 + wm + i * 16 + (lane >> 4) * 4;
      #pragma unroll
      for (int r = 0; r < 4; r++)
        C[(size_t)(rw0 + r) * N + col] = acc[i][j][r];
    }
  }
}

// ---------------------------------------------------------------------------
// fp32 GEMM for the tiny N=16 projections (Wa, Wb)
// ---------------------------------------------------------------------------
__global__ __launch_bounds__(256) void gemm_bt(
    const float* __restrict__ A, const float* __restrict__ B,
    float* __restrict__ C, int M, int N, int K) {
  __shared__ float As[16][68];
  __shared__ float Bs[16][68];
  const int bm = blockIdx.y, bn = blockIdx.x;
  const int t = threadIdx.x;
  const int tx = t & 15, ty = t >> 4;
  const int lrow = t >> 2;
  const int lk0  = (t & 3) * 4;
  const int arow = bm * 64 + lrow;
  const int brow = bn * 64 + lrow;
  const bool bvalid = brow < N;

  float acc[4][4];
  #pragma unroll
  for (int i = 0; i < 4; i++)
    #pragma unroll
    for (int j = 0; j < 4; j++) acc[i][j] = 0.f;

  for (int k0 = 0; k0 < K; k0 += 16) {
    float4 av = *(const float4*)&A[(size_t)arow * K + k0 + lk0];
    float4 bv = bvalid ? *(const float4*)&B[(size_t)brow * K + k0 + lk0]
                       : make_float4(0.f, 0.f, 0.f, 0.f);
    As[lk0+0][lrow] = av.x; As[lk0+1][lrow] = av.y;
    As[lk0+2][lrow] = av.z; As[lk0+3][lrow] = av.w;
    Bs[lk0+0][lrow] = bv.x; Bs[lk0+1][lrow] = bv.y;
    Bs[lk0+2][lrow] = bv.z; Bs[lk0+3][lrow] = bv.w;
    __syncthreads();
    #pragma unroll
    for (int kk = 0; kk < 16; kk++) {
      float4 a = *(const float4*)&As[kk][ty * 4];
      float4 b = *(const float4*)&Bs[kk][tx * 4];
      float ar[4] = {a.x, a.y, a.z, a.w};
      float br[4] = {b.x, b.y, b.z, b.w};
      #pragma unroll
      for (int i = 0; i < 4; i++)
        #pragma unroll
        for (int j = 0; j < 4; j++) acc[i][j] += ar[i] * br[j];
    }
    __syncthreads();
  }
  #pragma unroll
  for (int i = 0; i < 4; i++) {
    int r = bm * 64 + ty * 4 + i;
    #pragma unroll
    for (int j = 0; j < 4; j++) {
      int c = bn * 64 + tx * 4 + j;
      if (c < N) C[(size_t)r * N + c] = acc[i][j];
    }
  }
}

// ---------------------------------------------------------------------------
// conv + SiLU + l2norm for q/k
// ---------------------------------------------------------------------------
__global__ __launch_bounds__(128) void conv_qk_kernel(
    const float* __restrict__ pre, const float* __restrict__ cw,
    float* __restrict__ out, float scale) {
  const int s = blockIdx.x, h = blockIdx.y, t = threadIdx.x;
  const int c = h * 128 + t;
  const float4 w = *(const float4*)&cw[c * 4];
  float y = pre[(size_t)s * KEY_DIM + c] * w.w;
  if (s >= 1) y += pre[(size_t)(s-1) * KEY_DIM + c] * w.z;
  if (s >= 2) y += pre[(size_t)(s-2) * KEY_DIM + c] * w.y;
  if (s >= 3) y += pre[(size_t)(s-3) * KEY_DIM + c] * w.x;
  float v = y / (1.f + expf(-y));
  float ss = v * v;
  #pragma unroll
  for (int off = 1; off < 64; off <<= 1) ss += __shfl_xor(ss, off, 64);
  __shared__ float red[2];
  if ((t & 63) == 0) red[t >> 6] = ss;
  __syncthreads();
  float inv = scale / sqrtf(red[0] + red[1] + 1e-6f);
  out[((size_t)s * NH + h) * 128 + t] = v * inv;
}

// ---------------------------------------------------------------------------
// conv + SiLU for v
// ---------------------------------------------------------------------------
__global__ __launch_bounds__(256) void conv_v_kernel(
    const float* __restrict__ pre, const float* __restrict__ cw,
    float* __restrict__ out) {
  const int id = blockIdx.x * 256 + threadIdx.x;
  const int s = id >> 11, c = id & 2047;
  const float4 w = *(const float4*)&cw[c * 4];
  float y = pre[id] * w.w;
  if (s >= 1) y += pre[id - VAL_DIM]     * w.z;
  if (s >= 2) y += pre[id - 2*VAL_DIM]   * w.y;
  if (s >= 3) y += pre[id - 3*VAL_DIM]   * w.x;
  out[id] = y / (1.f + expf(-y));
}

// ---------------------------------------------------------------------------
// gl = -exp(A_log)*softplus(a+dt_bias)  (LOG decay), beta = sigmoid(b)
// ---------------------------------------------------------------------------
__global__ __launch_bounds__(256) void gb_kernel(
    const float* __restrict__ a_pre, const float* __restrict__ b_pre,
    const float* __restrict__ A_log, const float* __restrict__ dt_bias,
    float* __restrict__ gl, float* __restrict__ bv) {
  const int id = blockIdx.x * 256 + threadIdx.x;
  const int h = id & 15;
  float av = a_pre[id] + dt_bias[h];
  float sp = av > 20.f ? av : log1pf(expf(av));
  gl[id] = -expf(A_log[h]) * sp;
  bv[id] = 1.f / (1.f + expf(-b_pre[id]));
}

// ---------------------------------------------------------------------------
// Phase A v2: per (chunk, head). Gram from transposed kchT (conflict-free),
// forward substitution with solution in LDS (no per-thread arrays -> no
// spill). W stored row-major [j][dk]; U stored TRANSPOSED [n][j] for phaseB.
// grid (NVH, NCH), 256 threads.
// ---------------------------------------------------------------------------
__global__ __launch_bounds__(256) void phaseA_kernel(
    const float* __restrict__ kn, const float* __restrict__ vc,
    const float* __restrict__ gl, const float* __restrict__ bvv,
    __hip_bfloat16* __restrict__ Wb, __hip_bfloat16* __restrict__ UbT,
    float* __restrict__ Gbuf) {
  const int h = blockIdx.x, c = blockIdx.y, sh = h >> 1;
  const int t = threadIdx.x;
  __shared__ float kchT[128][68];   // [dk][j]
  __shared__ float vch[64][132];    // [j][n]
  __shared__ float mm[64][65];
  __shared__ float sol[64][257];    // odd stride: conflict-free per-column
  __shared__ float Gs[64], bet[64], lamB[64];

  {
    const int r = t >> 2, c0 = (t & 3) * 32;
    const float* krow = kn + (size_t)(c*64 + r)*KEY_DIM + sh*128 + c0;
    const float* vrow = vc + (size_t)(c*64 + r)*VAL_DIM + h*128 + c0;
    #pragma unroll
    for (int i = 0; i < 8; i++) {
      float4 kv = *(const float4*)&krow[4*i];
      kchT[c0+4*i+0][r] = kv.x; kchT[c0+4*i+1][r] = kv.y;
      kchT[c0+4*i+2][r] = kv.z; kchT[c0+4*i+3][r] = kv.w;
      *(float4*)&vch[r][c0 + 4*i] = *(const float4*)&vrow[4*i];
    }
  }
  if (t < 64) {
    float g = gl[(size_t)(c*64 + t)*NVH + h];
    #pragma unroll
    for (int off = 1; off < 64; off <<= 1) {
      float p = __shfl_up(g, off, 64);
      if (t >= off) g += p;
    }
    Gs[t] = g;
    float b = bvv[(size_t)(c*64 + t)*NVH + h];
    bet[t] = b;
    lamB[t] = b * expf(g);
    Gbuf[((size_t)c*NVH + h)*64 + t] = g;
  }
  __syncthreads();

  // Gram -> mm: thread (jb,lb) does a 4x4 tile; reads along j (conflict-free)
  {
    const int j0 = (t >> 4) * 4, l0 = (t & 15) * 4;
    float acc[4][4] = {};
    #pragma unroll 2
    for (int d = 0; d < 128; d++) {
      float4 kj = *(const float4*)&kchT[d][j0];
      float4 kl = *(const float4*)&kchT[d][l0];
      float aj[4] = {kj.x, kj.y, kj.z, kj.w};
      float al[4] = {kl.x, kl.y, kl.z, kl.w};
      #pragma unroll
      for (int i = 0; i < 4; i++)
        #pragma unroll
        for (int ii = 0; ii < 4; ii++)
          acc[i][ii] = fmaf(aj[i], al[ii], acc[i][ii]);
    }
    #pragma unroll
    for (int i = 0; i < 4; i++)
      #pragma unroll
      for (int ii = 0; ii < 4; ii++) {
        int j = j0 + i, l = l0 + ii;
        mm[j][l] = (l < j) ? bet[j] * expf(Gs[j] - Gs[l]) * acc[i][ii] : 0.f;
      }
  }
  __syncthreads();

  // Forward substitution, solution in LDS. Thread t owns column t
  // (t<128: W over dk-cols; t>=128: U over dv-cols). Own-column only: no
  // barriers needed; mm reads are wave-uniform broadcasts.
  {
    const bool isW = t < 128;
    const int col = t & 127;
    for (int j = 0; j < 64; j++) {
      float s0 = isW ? lamB[j] * kchT[col][j] : bet[j] * vch[j][col];
      float s1 = 0.f;
      int l = 0;
      for (; l + 1 < j; l += 2) {
        s0 = fmaf(-mm[j][l],   sol[l][t],   s0);
        s1 = fmaf(-mm[j][l+1], sol[l+1][t], s1);
      }
      if (l < j) s0 = fmaf(-mm[j][l], sol[l][t], s0);
      sol[j][t] = s0 + s1;
    }
  }
  // stores (own column; no barrier needed)
  if (t < 128) {
    const size_t base = ((size_t)c*NVH + h) * 64 * 128;
    for (int j = 0; j < 64; j++)
      Wb[base + j*128 + t] = __float2bfloat16(sol[j][t]);
  } else {
    const int n = t - 128;
    const size_t ub = (((size_t)c*NVH + h) * 128 + n) * 64;
    for (int j0 = 0; j0 < 64; j0 += 4) {
      union { unsigned long long u; __hip_bfloat16 b[4]; } p;
      #pragma unroll
      for (int i = 0; i < 4; i++) p.b[i] = __float2bfloat16(sol[j0+i][t]);
      *(unsigned long long*)&UbT[ub + j0] = p.u;
    }
  }
}

// ---------------------------------------------------------------------------
// Phase B v2: sequential over chunks; grid 32 = 16 heads x 2 value-halves.
// Per chunk: X = W S0, opart = (e^G q) S0, Delta = U - X (store row-major),
// S = e^{G_C} S + K^T diag(e^{G_C-G_j}) Delta.  U read from transposed UbT.
// ---------------------------------------------------------------------------
__global__ __launch_bounds__(256, 1) void phaseB_kernel(
    const float* __restrict__ qn, const float* __restrict__ kn,
    const __hip_bfloat16* __restrict__ Wb, const __hip_bfloat16* __restrict__ UbT,
    const float* __restrict__ Gbuf,
    __hip_bfloat16* __restrict__ Db, float* __restrict__ obuf) {
  const int h = blockIdx.x >> 1, vt = blockIdx.x & 1, sh = h >> 1;
  const int t = threadIdx.x, lane = t & 63, w = t >> 6;
  const int fm = lane & 15, fq = lane >> 4;

  __shared__ __hip_bfloat16 S16T[64][136];  // S0 mirror, [n_loc][dk]
  __shared__ __hip_bfloat16 kT[128][72];    // [dk][j]
  __shared__ __hip_bfloat16 q16[64][136];   // e^{G_j} q, [j][dk]
  __shared__ __hip_bfloat16 dT[64][72];     // e^{G_C-G_j} Delta, [n_loc][j]
  __shared__ float Gs[64];

  f32x4 Sacc[2][4];
  #pragma unroll
  for (int ti = 0; ti < 2; ti++)
    #pragma unroll
    for (int tj = 0; tj < 4; tj++) Sacc[ti][tj] = (f32x4){0.f,0.f,0.f,0.f};
  for (int i = t; i < 64*136/2; i += 256) ((unsigned int*)S16T)[i] = 0;
  __syncthreads();

  for (int c = 0; c < NCH; c++) {
    const int cb = (c*NVH + h) * 64;
    if (t < 64) Gs[t] = Gbuf[(size_t)cb + t];
    __syncthreads();
    {
      const int r = t >> 2, c0 = (t & 3) * 32;
      const float eg = expf(Gs[r]);
      const float* qrow = qn + (size_t)(c*64 + r)*KEY_DIM + sh*128 + c0;
      const float* krow = kn + (size_t)(c*64 + r)*KEY_DIM + sh*128 + c0;
      #pragma unroll
      for (int i = 0; i < 8; i++) {
        float4 qv = *(const float4*)&qrow[4*i];
        union { __hip_bfloat16 b[4]; unsigned long long u; } pq;
        pq.b[0] = __float2bfloat16(qv.x * eg);
        pq.b[1] = __float2bfloat16(qv.y * eg);
        pq.b[2] = __float2bfloat16(qv.z * eg);
        pq.b[3] = __float2bfloat16(qv.w * eg);
        *(unsigned long long*)&q16[r][c0 + 4*i] = pq.u;
        float4 kv = *(const float4*)&krow[4*i];
        kT[c0 + 4*i + 0][r] = __float2bfloat16(kv.x);
        kT[c0 + 4*i + 1][r] = __float2bfloat16(kv.y);
        kT[c0 + 4*i + 2][r] = __float2bfloat16(kv.z);
        kT[c0 + 4*i + 3][r] = __float2bfloat16(kv.w);
      }
    }
    __syncthreads();
    // (1)+(2): wave w handles chunk rows 16w..16w+15, n-tiles 0..3 (local)
    f32x4 aX[4], aO[4];
    #pragma unroll
    for (int tj = 0; tj < 4; tj++) {
      aX[tj] = (f32x4){0.f,0.f,0.f,0.f};
      aO[tj] = (f32x4){0.f,0.f,0.f,0.f};
    }
    #pragma unroll
    for (int k0 = 0; k0 < 128; k0 += 32) {
      short8 aW = *(const short8*)&Wb[(size_t)(cb + 16*w + fm)*128 + k0 + fq*8];
      short8 aQ = *(const short8*)&q16[16*w + fm][k0 + fq*8];
      #pragma unroll
      for (int tj = 0; tj < 4; tj++) {
        short8 b = *(const short8*)&S16T[16*tj + fm][k0 + fq*8];
        aX[tj] = __builtin_amdgcn_mfma_f32_16x16x32_bf16(aW, b, aX[tj], 0, 0, 0);
        aO[tj] = __builtin_amdgcn_mfma_f32_16x16x32_bf16(aQ, b, aO[tj], 0, 0, 0);
      }
    }
    const float gC = Gs[63];
    const int j0 = 16*w + fq*4;
    float er[4];
    #pragma unroll
    for (int r2 = 0; r2 < 4; r2++) er[r2] = expf(gC - Gs[j0 + r2]);
    #pragma unroll
    for (int tj = 0; tj < 4; tj++) {
      const int n = 16*tj + fm;                    // local n 0..63
      union { unsigned long long u; __hip_bfloat16 b[4]; } u4;
      u4.u = *(const unsigned long long*)
          &UbT[(((size_t)(c*NVH + h))*128 + vt*64 + n)*64 + j0];
      union { __hip_bfloat16 b[4]; unsigned long long u; } pd;
      #pragma unroll
      for (int r2 = 0; r2 < 4; r2++) {
        const int j = j0 + r2;
        float d = __bfloat162float(u4.b[r2]) - aX[tj][r2];
        Db[(size_t)(cb + j)*128 + vt*64 + n] = __float2bfloat16(d);
        pd.b[r2] = __float2bfloat16(d * er[r2]);
        obuf[((size_t)(c*64 + j)*NVH + h)*128 + vt*64 + n] = aO[tj][r2];
      }
      *(unsigned long long*)&dT[n][j0] = pd.u;
    }
    const float lamC = expf(gC);
    #pragma unroll
    for (int ti = 0; ti < 2; ti++)
      #pragma unroll
      for (int tj = 0; tj < 4; tj++)
        #pragma unroll
        for (int r2 = 0; r2 < 4; r2++) Sacc[ti][tj][r2] *= lamC;
    __syncthreads();
    // (3): S += K^T dT'   (wave w owns dk rows 32w..32w+31)
    #pragma unroll
    for (int ti = 0; ti < 2; ti++) {
      const int m0 = 32*w + 16*ti;
      #pragma unroll
      for (int kk0 = 0; kk0 < 64; kk0 += 32) {
        short8 aK = *(const short8*)&kT[m0 + fm][kk0 + fq*8];
        #pragma unroll
        for (int tj = 0; tj < 4; tj++) {
          short8 bD = *(const short8*)&dT[16*tj + fm][kk0 + fq*8];
          Sacc[ti][tj] = __builtin_amdgcn_mfma_f32_16x16x32_bf16(aK, bD, Sacc[ti][tj], 0, 0, 0);
        }
      }
    }
    #pragma unroll
    for (int ti = 0; ti < 2; ti++) {
      const int dk0 = 32*w + 16*ti + fq*4;
      #pragma unroll
      for (int tj = 0; tj < 4; tj++) {
        const int n = 16*tj + fm;
        union { __hip_bfloat16 b[4]; unsigned long long u; } ps;
        #pragma unroll
        for (int r2 = 0; r2 < 4; r2++) ps.b[r2] = __float2bfloat16(Sacc[ti][tj][r2]);
        *(unsigned long long*)&S16T[n][dk0] = ps.u;
      }
    }
    __syncthreads();
  }
}

// ---------------------------------------------------------------------------
// Phase C: o += P Delta, P[j][l] = e^{G_j-G_l} (q_j.k_l), l<=j. grid (NVH,NCH)
// ---------------------------------------------------------------------------
__global__ __launch_bounds__(256) void phaseC_kernel(
    const float* __restrict__ qn, const float* __restrict__ kn,
    const float* __restrict__ Gbuf, const __hip_bfloat16* __restrict__ Db,
    float* __restrict__ obuf) {
  const int h = blockIdx.x, c = blockIdx.y, sh = h >> 1;
  const int t = threadIdx.x;
  __shared__ float qch[64][132];
  __shared__ float kch[64][132];
  __shared__ float PT[64][68];              // [l][j]
  __shared__ __hip_bfloat16 dch[64][136];   // [l][n]
  __shared__ float Gs[64];

  {
    const int r = t >> 2, c0 = (t & 3) * 32;
    const float* qrow = qn + (size_t)(c*64 + r)*KEY_DIM + sh*128 + c0;
    const float* krow = kn + (size_t)(c*64 + r)*KEY_DIM + sh*128 + c0;
    #pragma unroll
    for (int i = 0; i < 8; i++) {
      *(float4*)&qch[r][c0 + 4*i] = *(const float4*)&qrow[4*i];
      *(float4*)&kch[r][c0 + 4*i] = *(const float4*)&krow[4*i];
    }
    const __hip_bfloat16* drow = Db + ((size_t)c*NVH + h)*64*128 + (size_t)r*128 + c0;
    #pragma unroll
    for (int i = 0; i < 4; i++)
      *(short8*)&dch[r][c0 + 8*i] = *(const short8*)&drow[8*i];
  }
  if (t < 64) Gs[t] = Gbuf[((size_t)c*NVH + h)*64 + t];
  __syncthreads();

  {
    const int jb = t >> 4, lb = t & 15;
    const int j0 = jb * 4, l0 = lb * 4;
    float acc[4][4] = {};
    for (int dd = 0; dd < 32; dd++) {
      const int d4 = ((dd + lb) & 31) * 4;
      float4 qj[4], kl[4];
      #pragma unroll
      for (int i = 0; i < 4; i++) {
        qj[i] = *(const float4*)&qch[j0 + i][d4];
        kl[i] = *(const float4*)&kch[l0 + i][d4];
      }
      #pragma unroll
      for (int i = 0; i < 4; i++)
        #pragma unroll
        for (int ii = 0; ii < 4; ii++)
          acc[i][ii] += qj[i].x*kl[ii].x + qj[i].y*kl[ii].y
                      + qj[i].z*kl[ii].z + qj[i].w*kl[ii].w;
    }
    #pragma unroll
    for (int i = 0; i < 4; i++)
      #pragma unroll
      for (int ii = 0; ii < 4; ii++) {
        int j = j0 + i, l = l0 + ii;
        PT[l][j] = (l <= j) ? expf(Gs[j] - Gs[l]) * acc[i][ii] : 0.f;
      }
  }
  __syncthreads();

  {
    const int j0 = (t >> 5) * 8;
    const int n0 = (t & 31) * 4;
    float acc2[8][4] = {};
    for (int l = 0; l < 64; l++) {
      float4 p0 = *(const float4*)&PT[l][j0];
      float4 p1 = *(const float4*)&PT[l][j0 + 4];
      float pj[8] = {p0.x,p0.y,p0.z,p0.w,p1.x,p1.y,p1.z,p1.w};
      float dv[4];
      #pragma unroll
      for (int ii = 0; ii < 4; ii++) dv[ii] = __bfloat162float(dch[l][n0 + ii]);
      #pragma unroll
      for (int i = 0; i < 8; i++)
        #pragma unroll
        for (int ii = 0; ii < 4; ii++)
          acc2[i][ii] += pj[i] * dv[ii];
    }
    #pragma unroll
    for (int i = 0; i < 8; i++) {
      float* orow = obuf + ((size_t)(c*64 + j0 + i)*NVH + h)*128 + n0;
      float4 o4 = *(const float4*)orow;
      o4.x += acc2[i][0]; o4.y += acc2[i][1];
      o4.z += acc2[i][2]; o4.w += acc2[i][3];
      *(float4*)orow = o4;
    }
  }
}

// ---------------------------------------------------------------------------
// Gated RMSNorm -> bf16
// ---------------------------------------------------------------------------
__global__ __launch_bounds__(128) void norm_kernel(
    const float* __restrict__ o, const float* __restrict__ gate,
    const float* __restrict__ w_norm, __hip_bfloat16* __restrict__ og) {
  const int s = blockIdx.x, h = blockIdx.y, t = threadIdx.x;
  const size_t idx = (size_t)s * VAL_DIM + h * 128 + t;
  float gt = gate[idx];
  float val = o[idx] * (gt / (1.f + expf(-gt)));
  float ss = val * val;
  #pragma unroll
  for (int off = 1; off < 64; off <<= 1) ss += __shfl_xor(ss, off, 64);
  __shared__ float red[2];
  if ((t & 63) == 0) red[t >> 6] = ss;
  __syncthreads();
  float ms = (red[0] + red[1]) * (1.f / 128.f);
  og[idx] = __float2bfloat16(val * (1.f / sqrtf(ms + 1e-6f)) * w_norm[t]);
}

// ---------------------------------------------------------------------------
extern "C" void kernel_launch(void* const* d_in, const int* in_sizes, int n_in,
                              void* d_out, int out_size, void* d_ws, size_t ws_size,
                              hipStream_t stream) {
  const float* x       = (const float*)d_in[0];
  const float* Wq      = (const float*)d_in[1];
  const float* Wk      = (const float*)d_in[2];
  const float* Wv      = (const float*)d_in[3];
  const float* Wa      = (const float*)d_in[4];
  const float* Wb_     = (const float*)d_in[5];
  const float* Wg      = (const float*)d_in[6];
  const float* Wo      = (const float*)d_in[7];
  const float* conv_q  = (const float*)d_in[8];
  const float* conv_k  = (const float*)d_in[9];
  const float* conv_v  = (const float*)d_in[10];
  const float* A_log   = (const float*)d_in[11];
  const float* dt_bias = (const float*)d_in[12];
  const float* w_norm  = (const float*)d_in[13];
  float* out = (float*)d_out;

  const size_t QK = (size_t)S_LEN * KEY_DIM;   // 4.19M
  const size_t SV = (size_t)S_LEN * VAL_DIM;   // 8.39M
  const size_t SM = (size_t)S_LEN * NVH;       // 65536

  float* W = (float*)d_ws;
  float* q_pre = W;
  float* k_pre = q_pre + QK;
  float* v_pre = k_pre + QK;       // SV floats; later: UbT (bf16) | Db (bf16)
  float* qn    = v_pre + SV;
  float* kn    = qn + QK;
  float* vcb   = kn + QK;          // SV floats; later: obuf
  float* a_pre = vcb + SV;
  float* b_pre = a_pre + SM;
  float* glb   = b_pre + SM;
  float* beta  = glb + SM;
  float* Gbuf  = beta + SM;        // NCH*NVH*64 = 65536
  __hip_bfloat16* xb = (__hip_bfloat16*)(Gbuf + SM);  // 8.39M bf16; later: Wb
  __hip_bfloat16* wb = xb + SV;                       // up to 4.19M bf16

  float* gate = q_pre;             // after convs
  float* obuf = vcb;               // after phase A
  __hip_bfloat16* ogb = (__hip_bfloat16*)kn;  // norm output
  __hip_bfloat16* Wbb = xb;                   // after gate gemm
  __hip_bfloat16* UbT = (__hip_bfloat16*)v_pre;
  __hip_bfloat16* Db  = (__hip_bfloat16*)(v_pre + SV/2);

  const int NC = 256 * 4;
  cast_f2b<<<(S_LEN*HID)/NC, 256, 0, stream>>>(x, xb, S_LEN*HID);

  cast_f2b<<<(KEY_DIM*HID)/NC, 256, 0, stream>>>(Wq, wb, KEY_DIM*HID);
  gemm_bf16_bt<<<dim3(KEY_DIM/128, S_LEN/128), 256, 0, stream>>>(xb, wb, q_pre, S_LEN, KEY_DIM, HID);
  cast_f2b<<<(KEY_DIM*HID)/NC, 256, 0, stream>>>(Wk, wb, KEY_DIM*HID);
  gemm_bf16_bt<<<dim3(KEY_DIM/128, S_LEN/128), 256, 0, stream>>>(xb, wb, k_pre, S_LEN, KEY_DIM, HID);
  cast_f2b<<<(VAL_DIM*HID)/NC, 256, 0, stream>>>(Wv, wb, VAL_DIM*HID);
  gemm_bf16_bt<<<dim3(VAL_DIM/128, S_LEN/128), 256, 0, stream>>>(xb, wb, v_pre, S_LEN, VAL_DIM, HID);
  gemm_bt<<<dim3(1, S_LEN/64), 256, 0, stream>>>(x, Wa, a_pre, S_LEN, NVH, HID);
  gemm_bt<<<dim3(1, S_LEN/64), 256, 0, stream>>>(x, Wb_, b_pre, S_LEN, NVH, HID);

  conv_qk_kernel<<<dim3(S_LEN, NH), 128, 0, stream>>>(q_pre, conv_q, qn, SCALE_Q);
  conv_qk_kernel<<<dim3(S_LEN, NH), 128, 0, stream>>>(k_pre, conv_k, kn, 1.f);
  conv_v_kernel<<<(S_LEN*VAL_DIM)/256, 256, 0, stream>>>(v_pre, conv_v, vcb);
  gb_kernel<<<(S_LEN*NVH)/256, 256, 0, stream>>>(a_pre, b_pre, A_log, dt_bias, glb, beta);

  cast_f2b<<<(VAL_DIM*HID)/NC, 256, 0, stream>>>(Wg, wb, VAL_DIM*HID);
  gemm_bf16_bt<<<dim3(VAL_DIM/128, S_LEN/128), 256, 0, stream>>>(xb, wb, gate, S_LEN, VAL_DIM, HID);

  // chunked delta-rule scan
  phaseA_kernel<<<dim3(NVH, NCH), 256, 0, stream>>>(kn, vcb, glb, beta, Wbb, UbT, Gbuf);
  phaseB_kernel<<<2*NVH, 256, 0, stream>>>(qn, kn, Wbb, UbT, Gbuf, Db, obuf);
  phaseC_kernel<<<dim3(NVH, NCH), 256, 0, stream>>>(qn, kn, Gbuf, Db, obuf);

  norm_kernel<<<dim3(S_LEN, NVH), 128, 0, stream>>>(obuf, gate, w_norm, ogb);

  cast_f2b<<<(HID*VAL_DIM)/NC, 256, 0, stream>>>(Wo, wb, HID*VAL_DIM);
  gemm_bf16_bt<<<dim3(HID/128, S_LEN/128), 256, 0, stream>>>(ogb, wb, out, S_LEN, HID, VAL_DIM);
}

// Round 5
// 1298.548 us; speedup vs baseline: 14.7835x; 1.0419x over previous
//
#include <hip/hip_runtime.h>
#include <hip/hip_bf16.h>
#include <math.h>

#define S_LEN 4096
#define HID   2048
#define NH    8
#define NVH   16
#define DK    128
#define DV    128
#define KEY_DIM  (NH*DK)    // 1024
#define VAL_DIM  (NVH*DV)   // 2048
#define SCALE_Q  0.08838834764831845f  // 128^-0.5
#define CCH 64              // chunk length
#define NCH (S_LEN/CCH)     // 64 chunks

typedef __attribute__((ext_vector_type(8))) short short8;   // 8 bf16
typedef __attribute__((ext_vector_type(4))) float f32x4;

// ---------------------------------------------------------------------------
// float -> bf16 cast
// ---------------------------------------------------------------------------
__global__ __launch_bounds__(256) void cast_f2b(
    const float* __restrict__ in, __hip_bfloat16* __restrict__ out, int n) {
  int i = (blockIdx.x * 256 + threadIdx.x) * 4;
  if (i >= n) return;
  float4 v = *(const float4*)&in[i];
  union { __hip_bfloat16 b[4]; short4 s; } u;
  u.b[0] = __float2bfloat16(v.x); u.b[1] = __float2bfloat16(v.y);
  u.b[2] = __float2bfloat16(v.z); u.b[3] = __float2bfloat16(v.w);
  *(short4*)&out[i] = u.s;
}

// ---------------------------------------------------------------------------
// bf16 MFMA GEMM: C[M,N](fp32) = A[M,K] @ B[N,K]^T  (m97 structure)
// ---------------------------------------------------------------------------
__device__ __forceinline__ void lds_load16(const __hip_bfloat16* g,
                                           __hip_bfloat16* l) {
  __builtin_amdgcn_global_load_lds(
      (const __attribute__((address_space(1))) unsigned int*)g,
      (__attribute__((address_space(3))) unsigned int*)l, 16, 0, 0);
}

__global__ __launch_bounds__(256) void gemm_bf16_bt(
    const __hip_bfloat16* __restrict__ A, const __hip_bfloat16* __restrict__ B,
    float* __restrict__ C, int M, int N, int K) {
  __shared__ __hip_bfloat16 sA[128 * 32];
  __shared__ __hip_bfloat16 sB[128 * 32];
  const int t = threadIdx.x;
  const int wave = t >> 6, lane = t & 63;
  const int bm = blockIdx.y, bn = blockIdx.x;
  const int wm = (wave & 1) * 64, wn = (wave >> 1) * 64;

  f32x4 zero = {0.f, 0.f, 0.f, 0.f};
  f32x4 acc[4][4];
  #pragma unroll
  for (int i = 0; i < 4; i++)
    #pragma unroll
    for (int j = 0; j < 4; j++) acc[i][j] = zero;

  const int r0 = t >> 2,        c0 = (t & 3) * 8;
  const int r1 = (256 + t) >> 2, c1 = ((256 + t) & 3) * 8;
  const __hip_bfloat16* gA0 = A + (size_t)(bm * 128 + r0) * K + c0;
  const __hip_bfloat16* gA1 = A + (size_t)(bm * 128 + r1) * K + c1;
  const __hip_bfloat16* gB0 = B + (size_t)(bn * 128 + r0) * K + c0;
  const __hip_bfloat16* gB1 = B + (size_t)(bn * 128 + r1) * K + c1;
  __hip_bfloat16* lA0 = sA + (size_t)(wave * 64) * 8;
  __hip_bfloat16* lA1 = sA + (size_t)(256 + wave * 64) * 8;
  __hip_bfloat16* lB0 = sB + (size_t)(wave * 64) * 8;
  __hip_bfloat16* lB1 = sB + (size_t)(256 + wave * 64) * 8;

  const int fm = lane & 15, fk = (lane >> 4) * 8;

  for (int k0 = 0; k0 < K; k0 += 32) {
    lds_load16(gA0, lA0); lds_load16(gA1, lA1);
    lds_load16(gB0, lB0); lds_load16(gB1, lB1);
    gA0 += 32; gA1 += 32; gB0 += 32; gB1 += 32;
    __syncthreads();
    short8 a[4], b[4];
    #pragma unroll
    for (int i = 0; i < 4; i++)
      a[i] = *(const short8*)&sA[(size_t)(wm + i * 16 + fm) * 32 + fk];
    #pragma unroll
    for (int j = 0; j < 4; j++)
      b[j] = *(const short8*)&sB[(size_t)(wn + j * 16 + fm) * 32 + fk];
    #pragma unroll
    for (int i = 0; i < 4; i++)
      #pragma unroll
      for (int j = 0; j < 4; j++)
        acc[i][j] = __builtin_amdgcn_mfma_f32_16x16x32_bf16(a[i], b[j], acc[i][j], 0, 0, 0);
    __syncthreads();
  }
  #pragma unroll
  for (int i = 0; i < 4; i++) {
    #pragma unroll
    for (int j = 0; j < 4; j++) {
      int col = bn * 128 + wn + j * 16 + (lane & 15);
      int rw0 = bm * 128 + wm + i * 16 + (lane >> 4) * 4;
      #pragma unroll
      for (int r = 0; r < 4; r++)
        C[(size_t)(rw0 + r) * N + col] = acc[i][j][r];
    }
  }
}

// ---------------------------------------------------------------------------
// fp32 GEMM for the tiny N=16 projections (Wa, Wb)
// ---------------------------------------------------------------------------
__global__ __launch_bounds__(256) void gemm_bt(
    const float* __restrict__ A, const float* __restrict__ B,
    float* __restrict__ C, int M, int N, int K) {
  __shared__ float As[16][68];
  __shared__ float Bs[16][68];
  const int bm = blockIdx.y, bn = blockIdx.x;
  const int t = threadIdx.x;
  const int tx = t & 15, ty = t >> 4;
  const int lrow = t >> 2;
  const int lk0  = (t & 3) * 4;
  const int arow = bm * 64 + lrow;
  const int brow = bn * 64 + lrow;
  const bool bvalid = brow < N;

  float acc[4][4];
  #pragma unroll
  for (int i = 0; i < 4; i++)
    #pragma unroll
    for (int j = 0; j < 4; j++) acc[i][j] = 0.f;

  for (int k0 = 0; k0 < K; k0 += 16) {
    float4 av = *(const float4*)&A[(size_t)arow * K + k0 + lk0];
    float4 bv = bvalid ? *(const float4*)&B[(size_t)brow * K + k0 + lk0]
                       : make_float4(0.f, 0.f, 0.f, 0.f);
    As[lk0+0][lrow] = av.x; As[lk0+1][lrow] = av.y;
    As[lk0+2][lrow] = av.z; As[lk0+3][lrow] = av.w;
    Bs[lk0+0][lrow] = bv.x; Bs[lk0+1][lrow] = bv.y;
    Bs[lk0+2][lrow] = bv.z; Bs[lk0+3][lrow] = bv.w;
    __syncthreads();
    #pragma unroll
    for (int kk = 0; kk < 16; kk++) {
      float4 a = *(const float4*)&As[kk][ty * 4];
      float4 b = *(const float4*)&Bs[kk][tx * 4];
      float ar[4] = {a.x, a.y, a.z, a.w};
      float br[4] = {b.x, b.y, b.z, b.w};
      #pragma unroll
      for (int i = 0; i < 4; i++)
        #pragma unroll
        for (int j = 0; j < 4; j++) acc[i][j] += ar[i] * br[j];
    }
    __syncthreads();
  }
  #pragma unroll
  for (int i = 0; i < 4; i++) {
    int r = bm * 64 + ty * 4 + i;
    #pragma unroll
    for (int j = 0; j < 4; j++) {
      int c = bn * 64 + tx * 4 + j;
      if (c < N) C[(size_t)r * N + c] = acc[i][j];
    }
  }
}

// ---------------------------------------------------------------------------
// conv + SiLU + l2norm for q/k
// ---------------------------------------------------------------------------
__global__ __launch_bounds__(128) void conv_qk_kernel(
    const float* __restrict__ pre, const float* __restrict__ cw,
    float* __restrict__ out, float scale) {
  const int s = blockIdx.x, h = blockIdx.y, t = threadIdx.x;
  const int c = h * 128 + t;
  const float4 w = *(const float4*)&cw[c * 4];
  float y = pre[(size_t)s * KEY_DIM + c] * w.w;
  if (s >= 1) y += pre[(size_t)(s-1) * KEY_DIM + c] * w.z;
  if (s >= 2) y += pre[(size_t)(s-2) * KEY_DIM + c] * w.y;
  if (s >= 3) y += pre[(size_t)(s-3) * KEY_DIM + c] * w.x;
  float v = y / (1.f + expf(-y));
  float ss = v * v;
  #pragma unroll
  for (int off = 1; off < 64; off <<= 1) ss += __shfl_xor(ss, off, 64);
  __shared__ float red[2];
  if ((t & 63) == 0) red[t >> 6] = ss;
  __syncthreads();
  float inv = scale / sqrtf(red[0] + red[1] + 1e-6f);
  out[((size_t)s * NH + h) * 128 + t] = v * inv;
}

// ---------------------------------------------------------------------------
// conv + SiLU for v
// ---------------------------------------------------------------------------
__global__ __launch_bounds__(256) void conv_v_kernel(
    const float* __restrict__ pre, const float* __restrict__ cw,
    float* __restrict__ out) {
  const int id = blockIdx.x * 256 + threadIdx.x;
  const int s = id >> 11, c = id & 2047;
  const float4 w = *(const float4*)&cw[c * 4];
  float y = pre[id] * w.w;
  if (s >= 1) y += pre[id - VAL_DIM]     * w.z;
  if (s >= 2) y += pre[id - 2*VAL_DIM]   * w.y;
  if (s >= 3) y += pre[id - 3*VAL_DIM]   * w.x;
  out[id] = y / (1.f + expf(-y));
}

// ---------------------------------------------------------------------------
// gl = -exp(A_log)*softplus(a+dt_bias)  (LOG decay), beta = sigmoid(b)
// ---------------------------------------------------------------------------
__global__ __launch_bounds__(256) void gb_kernel(
    const float* __restrict__ a_pre, const float* __restrict__ b_pre,
    const float* __restrict__ A_log, const float* __restrict__ dt_bias,
    float* __restrict__ gl, float* __restrict__ bv) {
  const int id = blockIdx.x * 256 + threadIdx.x;
  const int h = id & 15;
  float av = a_pre[id] + dt_bias[h];
  float sp = av > 20.f ? av : log1pf(expf(av));
  gl[id] = -expf(A_log[h]) * sp;
  bv[id] = 1.f / (1.f + expf(-b_pre[id]));
}

// ---------------------------------------------------------------------------
// Phase A v2 (unchanged from R4)
// ---------------------------------------------------------------------------
__global__ __launch_bounds__(256) void phaseA_kernel(
    const float* __restrict__ kn, const float* __restrict__ vc,
    const float* __restrict__ gl, const float* __restrict__ bvv,
    __hip_bfloat16* __restrict__ Wb, __hip_bfloat16* __restrict__ UbT,
    float* __restrict__ Gbuf) {
  const int h = blockIdx.x, c = blockIdx.y, sh = h >> 1;
  const int t = threadIdx.x;
  __shared__ float kchT[128][68];   // [dk][j]
  __shared__ float vch[64][132];    // [j][n]
  __shared__ float mm[64][65];
  __shared__ float sol[64][257];    // odd stride: conflict-free per-column
  __shared__ float Gs[64], bet[64], lamB[64];

  {
    const int r = t >> 2, c0 = (t & 3) * 32;
    const float* krow = kn + (size_t)(c*64 + r)*KEY_DIM + sh*128 + c0;
    const float* vrow = vc + (size_t)(c*64 + r)*VAL_DIM + h*128 + c0;
    #pragma unroll
    for (int i = 0; i < 8; i++) {
      float4 kv = *(const float4*)&krow[4*i];
      kchT[c0+4*i+0][r] = kv.x; kchT[c0+4*i+1][r] = kv.y;
      kchT[c0+4*i+2][r] = kv.z; kchT[c0+4*i+3][r] = kv.w;
      *(float4*)&vch[r][c0 + 4*i] = *(const float4*)&vrow[4*i];
    }
  }
  if (t < 64) {
    float g = gl[(size_t)(c*64 + t)*NVH + h];
    #pragma unroll
    for (int off = 1; off < 64; off <<= 1) {
      float p = __shfl_up(g, off, 64);
      if (t >= off) g += p;
    }
    Gs[t] = g;
    float b = bvv[(size_t)(c*64 + t)*NVH + h];
    bet[t] = b;
    lamB[t] = b * expf(g);
    Gbuf[((size_t)c*NVH + h)*64 + t] = g;
  }
  __syncthreads();

  {
    const int j0 = (t >> 4) * 4, l0 = (t & 15) * 4;
    float acc[4][4] = {};
    #pragma unroll 2
    for (int d = 0; d < 128; d++) {
      float4 kj = *(const float4*)&kchT[d][j0];
      float4 kl = *(const float4*)&kchT[d][l0];
      float aj[4] = {kj.x, kj.y, kj.z, kj.w};
      float al[4] = {kl.x, kl.y, kl.z, kl.w};
      #pragma unroll
      for (int i = 0; i < 4; i++)
        #pragma unroll
        for (int ii = 0; ii < 4; ii++)
          acc[i][ii] = fmaf(aj[i], al[ii], acc[i][ii]);
    }
    #pragma unroll
    for (int i = 0; i < 4; i++)
      #pragma unroll
      for (int ii = 0; ii < 4; ii++) {
        int j = j0 + i, l = l0 + ii;
        mm[j][l] = (l < j) ? bet[j] * expf(Gs[j] - Gs[l]) * acc[i][ii] : 0.f;
      }
  }
  __syncthreads();

  {
    const bool isW = t < 128;
    const int col = t & 127;
    for (int j = 0; j < 64; j++) {
      float s0 = isW ? lamB[j] * kchT[col][j] : bet[j] * vch[j][col];
      float s1 = 0.f;
      int l = 0;
      for (; l + 1 < j; l += 2) {
        s0 = fmaf(-mm[j][l],   sol[l][t],   s0);
        s1 = fmaf(-mm[j][l+1], sol[l+1][t], s1);
      }
      if (l < j) s0 = fmaf(-mm[j][l], sol[l][t], s0);
      sol[j][t] = s0 + s1;
    }
  }
  if (t < 128) {
    const size_t base = ((size_t)c*NVH + h) * 64 * 128;
    for (int j = 0; j < 64; j++)
      Wb[base + j*128 + t] = __float2bfloat16(sol[j][t]);
  } else {
    const int n = t - 128;
    const size_t ub = (((size_t)c*NVH + h) * 128 + n) * 64;
    for (int j0 = 0; j0 < 64; j0 += 4) {
      union { unsigned long long u; __hip_bfloat16 b[4]; } p;
      #pragma unroll
      for (int i = 0; i < 4; i++) p.b[i] = __float2bfloat16(sol[j0+i][t]);
      *(unsigned long long*)&UbT[ub + j0] = p.u;
    }
  }
}

// ---------------------------------------------------------------------------
// Phase B v3: software-pipelined chunk loop. grid 32 = 16 heads x 2 v-halves.
// Prefetch chunk c+1's q/k/W/U/G into registers during chunk c's compute;
// conflict-free kT transpose via b128 row writes.
// ---------------------------------------------------------------------------
__global__ __launch_bounds__(256, 1) void phaseB_kernel(
    const float* __restrict__ qn, const float* __restrict__ kn,
    const __hip_bfloat16* __restrict__ Wb, const __hip_bfloat16* __restrict__ UbT,
    const float* __restrict__ Gbuf,
    __hip_bfloat16* __restrict__ Db, float* __restrict__ obuf) {
  const int h = blockIdx.x >> 1, vt = blockIdx.x & 1, sh = h >> 1;
  const int t = threadIdx.x, lane = t & 63, w = t >> 6;
  const int fm = lane & 15, fq = lane >> 4;

  __shared__ __hip_bfloat16 S16T[64][136];  // S0 mirror (bf16), [n_loc][dk]
  __shared__ __hip_bfloat16 kT[128][72];    // [dk][j]
  __shared__ __hip_bfloat16 q16[64][136];   // e^{G_j} q, [j][dk]
  __shared__ __hip_bfloat16 dT[64][72];     // e^{G_C-G_j} Delta, [n_loc][j]
  __shared__ float Gs[64];

  // staging assignments
  const int qr = t >> 2, qc = (t & 3) * 32;          // q: one row, 32 cols
  const int kj = (t & 7) * 8, kd = (t >> 3) * 4;     // k: 8 rows x 4 dk (transpose)
  const int j0 = 16*w + fq*4;                        // epilogue rows

  f32x4 Sacc[2][4];
  #pragma unroll
  for (int ti = 0; ti < 2; ti++)
    #pragma unroll
    for (int tj = 0; tj < 4; tj++) Sacc[ti][tj] = (f32x4){0.f,0.f,0.f,0.f};
  for (int i = t; i < 64*136/2; i += 256) ((unsigned int*)S16T)[i] = 0;

  float4 qreg[8], kreg[8];
  short8 Wnext[4], Wcur[4];
  unsigned long long Unext[4], Ucur[4];
  float gq, gl64;

  auto prefetch = [&](int c) {
    const int cb = (c*NVH + h) * 64;
    const float* qrow = qn + (size_t)(c*64 + qr)*KEY_DIM + sh*128 + qc;
    #pragma unroll
    for (int i = 0; i < 8; i++) qreg[i] = *(const float4*)&qrow[4*i];
    #pragma unroll
    for (int jj = 0; jj < 8; jj++)
      kreg[jj] = *(const float4*)&kn[(size_t)(c*64 + kj + jj)*KEY_DIM + sh*128 + kd];
    #pragma unroll
    for (int k4 = 0; k4 < 4; k4++)
      Wnext[k4] = *(const short8*)&Wb[(size_t)(cb + 16*w + fm)*128 + k4*32 + fq*8];
    #pragma unroll
    for (int tj = 0; tj < 4; tj++)
      Unext[tj] = *(const unsigned long long*)
          &UbT[(((size_t)c*NVH + h)*128 + vt*64 + 16*tj + fm)*64 + j0];
    gq = Gbuf[(size_t)cb + qr];
    if (t < 64) gl64 = Gbuf[(size_t)cb + t];
  };

  auto stage = [&]() {
    if (t < 64) Gs[t] = gl64;
    const float eg = expf(gq);
    #pragma unroll
    for (int i = 0; i < 8; i++) {
      union { __hip_bfloat16 b[4]; unsigned long long u; } pq;
      pq.b[0] = __float2bfloat16(qreg[i].x * eg);
      pq.b[1] = __float2bfloat16(qreg[i].y * eg);
      pq.b[2] = __float2bfloat16(qreg[i].z * eg);
      pq.b[3] = __float2bfloat16(qreg[i].w * eg);
      *(unsigned long long*)&q16[qr][qc + 4*i] = pq.u;
    }
    const float* kf = (const float*)kreg;
    #pragma unroll
    for (int dd = 0; dd < 4; dd++) {
      union { __hip_bfloat16 b[8]; short8 s; } pk;
      #pragma unroll
      for (int jj = 0; jj < 8; jj++) pk.b[jj] = __float2bfloat16(kf[jj*4 + dd]);
      *(short8*)&kT[kd + dd][kj] = pk.s;
    }
  };

  prefetch(0);
  #pragma unroll
  for (int k4 = 0; k4 < 4; k4++) Wcur[k4] = Wnext[k4];
  #pragma unroll
  for (int tj = 0; tj < 4; tj++) Ucur[tj] = Unext[tj];
  __syncthreads();          // S16T zero-init visible
  stage();
  __syncthreads();          // chunk-0 staging visible

  for (int c = 0; c < NCH; c++) {
    // issue prefetch for c+1 (independent; drains under compute)
    prefetch(c + 1 < NCH ? c + 1 : 0);

    // (1)+(2): X = W S0, opart = q16 S0
    f32x4 aX[4], aO[4];
    #pragma unroll
    for (int tj = 0; tj < 4; tj++) {
      aX[tj] = (f32x4){0.f,0.f,0.f,0.f};
      aO[tj] = (f32x4){0.f,0.f,0.f,0.f};
    }
    #pragma unroll
    for (int k4 = 0; k4 < 4; k4++) {
      short8 aQ = *(const short8*)&q16[16*w + fm][k4*32 + fq*8];
      #pragma unroll
      for (int tj = 0; tj < 4; tj++) {
        short8 b = *(const short8*)&S16T[16*tj + fm][k4*32 + fq*8];
        aX[tj] = __builtin_amdgcn_mfma_f32_16x16x32_bf16(Wcur[k4], b, aX[tj], 0, 0, 0);
        aO[tj] = __builtin_amdgcn_mfma_f32_16x16x32_bf16(aQ,       b, aO[tj], 0, 0, 0);
      }
    }
    // epilogue: Delta, dT, stores
    const int cb = (c*NVH + h) * 64;
    const float gC = Gs[63];
    float er[4];
    #pragma unroll
    for (int r2 = 0; r2 < 4; r2++) er[r2] = expf(gC - Gs[j0 + r2]);
    #pragma unroll
    for (int tj = 0; tj < 4; tj++) {
      const int n = 16*tj + fm;
      union { unsigned long long u; __hip_bfloat16 b[4]; } u4;
      u4.u = Ucur[tj];
      union { __hip_bfloat16 b[4]; unsigned long long u; } pd;
      #pragma unroll
      for (int r2 = 0; r2 < 4; r2++) {
        const int j = j0 + r2;
        float d = __bfloat162float(u4.b[r2]) - aX[tj][r2];
        Db[(size_t)(cb + j)*128 + vt*64 + n] = __float2bfloat16(d);
        pd.b[r2] = __float2bfloat16(d * er[r2]);
        obuf[((size_t)(c*64 + j)*NVH + h)*128 + vt*64 + n] = aO[tj][r2];
      }
      *(unsigned long long*)&dT[n][j0] = pd.u;
    }
    // decay S
    const float lamC = expf(gC);
    #pragma unroll
    for (int ti = 0; ti < 2; ti++)
      #pragma unroll
      for (int tj = 0; tj < 4; tj++)
        #pragma unroll
        for (int r2 = 0; r2 < 4; r2++) Sacc[ti][tj][r2] *= lamC;
    __syncthreads();   // dT visible; all (1)/(2) S16T reads done
    // (3): S += K^T dT'
    #pragma unroll
    for (int ti = 0; ti < 2; ti++) {
      const int m0 = 32*w + 16*ti;
      #pragma unroll
      for (int kk0 = 0; kk0 < 64; kk0 += 32) {
        short8 aK = *(const short8*)&kT[m0 + fm][kk0 + fq*8];
        #pragma unroll
        for (int tj = 0; tj < 4; tj++) {
          short8 bD = *(const short8*)&dT[16*tj + fm][kk0 + fq*8];
          Sacc[ti][tj] = __builtin_amdgcn_mfma_f32_16x16x32_bf16(aK, bD, Sacc[ti][tj], 0, 0, 0);
        }
      }
    }
    // refresh bf16 mirror
    #pragma unroll
    for (int ti = 0; ti < 2; ti++) {
      const int dk0 = 32*w + 16*ti + fq*4;
      #pragma unroll
      for (int tj = 0; tj < 4; tj++) {
        const int n = 16*tj + fm;
        union { __hip_bfloat16 b[4]; unsigned long long u; } ps;
        #pragma unroll
        for (int r2 = 0; r2 < 4; r2++) ps.b[r2] = __float2bfloat16(Sacc[ti][tj][r2]);
        *(unsigned long long*)&S16T[n][dk0] = ps.u;
      }
    }
    __syncthreads();   // compute done; LDS q16/kT/Gs free to overwrite
    stage();           // write c+1 regs -> LDS
    #pragma unroll
    for (int k4 = 0; k4 < 4; k4++) Wcur[k4] = Wnext[k4];
    #pragma unroll
    for (int tj = 0; tj < 4; tj++) Ucur[tj] = Unext[tj];
    __syncthreads();   // c+1 staging visible
  }
}

// ---------------------------------------------------------------------------
// Phase C (unchanged from R4)
// ---------------------------------------------------------------------------
__global__ __launch_bounds__(256) void phaseC_kernel(
    const float* __restrict__ qn, const float* __restrict__ kn,
    const float* __restrict__ Gbuf, const __hip_bfloat16* __restrict__ Db,
    float* __restrict__ obuf) {
  const int h = blockIdx.x, c = blockIdx.y, sh = h >> 1;
  const int t = threadIdx.x;
  __shared__ float qch[64][132];
  __shared__ float kch[64][132];
  __shared__ float PT[64][68];              // [l][j]
  __shared__ __hip_bfloat16 dch[64][136];   // [l][n]
  __shared__ float Gs[64];

  {
    const int r = t >> 2, c0 = (t & 3) * 32;
    const float* qrow = qn + (size_t)(c*64 + r)*KEY_DIM + sh*128 + c0;
    const float* krow = kn + (size_t)(c*64 + r)*KEY_DIM + sh*128 + c0;
    #pragma unroll
    for (int i = 0; i < 8; i++) {
      *(float4*)&qch[r][c0 + 4*i] = *(const float4*)&qrow[4*i];
      *(float4*)&kch[r][c0 + 4*i] = *(const float4*)&krow[4*i];
    }
    const __hip_bfloat16* drow = Db + ((size_t)c*NVH + h)*64*128 + (size_t)r*128 + c0;
    #pragma unroll
    for (int i = 0; i < 4; i++)
      *(short8*)&dch[r][c0 + 8*i] = *(const short8*)&drow[8*i];
  }
  if (t < 64) Gs[t] = Gbuf[((size_t)c*NVH + h)*64 + t];
  __syncthreads();

  {
    const int jb = t >> 4, lb = t & 15;
    const int j0 = jb * 4, l0 = lb * 4;
    float acc[4][4] = {};
    for (int dd = 0; dd < 32; dd++) {
      const int d4 = ((dd + lb) & 31) * 4;
      float4 qj[4], kl[4];
      #pragma unroll
      for (int i = 0; i < 4; i++) {
        qj[i] = *(const float4*)&qch[j0 + i][d4];
        kl[i] = *(const float4*)&kch[l0 + i][d4];
      }
      #pragma unroll
      for (int i = 0; i < 4; i++)
        #pragma unroll
        for (int ii = 0; ii < 4; ii++)
          acc[i][ii] += qj[i].x*kl[ii].x + qj[i].y*kl[ii].y
                      + qj[i].z*kl[ii].z + qj[i].w*kl[ii].w;
    }
    #pragma unroll
    for (int i = 0; i < 4; i++)
      #pragma unroll
      for (int ii = 0; ii < 4; ii++) {
        int j = j0 + i, l = l0 + ii;
        PT[l][j] = (l <= j) ? expf(Gs[j] - Gs[l]) * acc[i][ii] : 0.f;
      }
  }
  __syncthreads();

  {
    const int j0 = (t >> 5) * 8;
    const int n0 = (t & 31) * 4;
    float acc2[8][4] = {};
    for (int l = 0; l < 64; l++) {
      float4 p0 = *(const float4*)&PT[l][j0];
      float4 p1 = *(const float4*)&PT[l][j0 + 4];
      float pj[8] = {p0.x,p0.y,p0.z,p0.w,p1.x,p1.y,p1.z,p1.w};
      float dv[4];
      #pragma unroll
      for (int ii = 0; ii < 4; ii++) dv[ii] = __bfloat162float(dch[l][n0 + ii]);
      #pragma unroll
      for (int i = 0; i < 8; i++)
        #pragma unroll
        for (int ii = 0; ii < 4; ii++)
          acc2[i][ii] += pj[i] * dv[ii];
    }
    #pragma unroll
    for (int i = 0; i < 8; i++) {
      float* orow = obuf + ((size_t)(c*64 + j0 + i)*NVH + h)*128 + n0;
      float4 o4 = *(const float4*)orow;
      o4.x += acc2[i][0]; o4.y += acc2[i][1];
      o4.z += acc2[i][2]; o4.w += acc2[i][3];
      *(float4*)orow = o4;
    }
  }
}

// ---------------------------------------------------------------------------
// Gated RMSNorm -> bf16
// ---------------------------------------------------------------------------
__global__ __launch_bounds__(128) void norm_kernel(
    const float* __restrict__ o, const float* __restrict__ gate,
    const float* __restrict__ w_norm, __hip_bfloat16* __restrict__ og) {
  const int s = blockIdx.x, h = blockIdx.y, t = threadIdx.x;
  const size_t idx = (size_t)s * VAL_DIM + h * 128 + t;
  float gt = gate[idx];
  float val = o[idx] * (gt / (1.f + expf(-gt)));
  float ss = val * val;
  #pragma unroll
  for (int off = 1; off < 64; off <<= 1) ss += __shfl_xor(ss, off, 64);
  __shared__ float red[2];
  if ((t & 63) == 0) red[t >> 6] = ss;
  __syncthreads();
  float ms = (red[0] + red[1]) * (1.f / 128.f);
  og[idx] = __float2bfloat16(val * (1.f / sqrtf(ms + 1e-6f)) * w_norm[t]);
}

// ---------------------------------------------------------------------------
extern "C" void kernel_launch(void* const* d_in, const int* in_sizes, int n_in,
                              void* d_out, int out_size, void* d_ws, size_t ws_size,
                              hipStream_t stream) {
  const float* x       = (const float*)d_in[0];
  const float* Wq      = (const float*)d_in[1];
  const float* Wk      = (const float*)d_in[2];
  const float* Wv      = (const float*)d_in[3];
  const float* Wa      = (const float*)d_in[4];
  const float* Wb_     = (const float*)d_in[5];
  const float* Wg      = (const float*)d_in[6];
  const float* Wo      = (const float*)d_in[7];
  const float* conv_q  = (const float*)d_in[8];
  const float* conv_k  = (const float*)d_in[9];
  const float* conv_v  = (const float*)d_in[10];
  const float* A_log   = (const float*)d_in[11];
  const float* dt_bias = (const float*)d_in[12];
  const float* w_norm  = (const float*)d_in[13];
  float* out = (float*)d_out;

  const size_t QK = (size_t)S_LEN * KEY_DIM;   // 4.19M
  const size_t SV = (size_t)S_LEN * VAL_DIM;   // 8.39M
  const size_t SM = (size_t)S_LEN * NVH;       // 65536

  float* W = (float*)d_ws;
  float* q_pre = W;
  float* k_pre = q_pre + QK;
  float* v_pre = k_pre + QK;       // SV floats; later: UbT (bf16) | Db (bf16)
  float* qn    = v_pre + SV;
  float* kn    = qn + QK;
  float* vcb   = kn + QK;          // SV floats; later: obuf
  float* a_pre = vcb + SV;
  float* b_pre = a_pre + SM;
  float* glb   = b_pre + SM;
  float* beta  = glb + SM;
  float* Gbuf  = beta + SM;        // NCH*NVH*64 = 65536
  __hip_bfloat16* xb = (__hip_bfloat16*)(Gbuf + SM);  // 8.39M bf16; later: Wb
  __hip_bfloat16* wb = xb + SV;                       // up to 4.19M bf16

  float* gate = q_pre;             // after convs
  float* obuf = vcb;               // after phase A
  __hip_bfloat16* ogb = (__hip_bfloat16*)kn;  // norm output
  __hip_bfloat16* Wbb = xb;                   // after gate gemm
  __hip_bfloat16* UbT = (__hip_bfloat16*)v_pre;
  __hip_bfloat16* Db  = (__hip_bfloat16*)(v_pre + SV/2);

  const int NC = 256 * 4;
  cast_f2b<<<(S_LEN*HID)/NC, 256, 0, stream>>>(x, xb, S_LEN*HID);

  cast_f2b<<<(KEY_DIM*HID)/NC, 256, 0, stream>>>(Wq, wb, KEY_DIM*HID);
  gemm_bf16_bt<<<dim3(KEY_DIM/128, S_LEN/128), 256, 0, stream>>>(xb, wb, q_pre, S_LEN, KEY_DIM, HID);
  cast_f2b<<<(KEY_DIM*HID)/NC, 256, 0, stream>>>(Wk, wb, KEY_DIM*HID);
  gemm_bf16_bt<<<dim3(KEY_DIM/128, S_LEN/128), 256, 0, stream>>>(xb, wb, k_pre, S_LEN, KEY_DIM, HID);
  cast_f2b<<<(VAL_DIM*HID)/NC, 256, 0, stream>>>(Wv, wb, VAL_DIM*HID);
  gemm_bf16_bt<<<dim3(VAL_DIM/128, S_LEN/128), 256, 0, stream>>>(xb, wb, v_pre, S_LEN, VAL_DIM, HID);
  gemm_bt<<<dim3(1, S_LEN/64), 256, 0, stream>>>(x, Wa, a_pre, S_LEN, NVH, HID);
  gemm_bt<<<dim3(1, S_LEN/64), 256, 0, stream>>>(x, Wb_, b_pre, S_LEN, NVH, HID);

  conv_qk_kernel<<<dim3(S_LEN, NH), 128, 0, stream>>>(q_pre, conv_q, qn, SCALE_Q);
  conv_qk_kernel<<<dim3(S_LEN, NH), 128, 0, stream>>>(k_pre, conv_k, kn, 1.f);
  conv_v_kernel<<<(S_LEN*VAL_DIM)/256, 256, 0, stream>>>(v_pre, conv_v, vcb);
  gb_kernel<<<(S_LEN*NVH)/256, 256, 0, stream>>>(a_pre, b_pre, A_log, dt_bias, glb, beta);

  cast_f2b<<<(VAL_DIM*HID)/NC, 256, 0, stream>>>(Wg, wb, VAL_DIM*HID);
  gemm_bf16_bt<<<dim3(VAL_DIM/128, S_LEN/128), 256, 0, stream>>>(xb, wb, gate, S_LEN, VAL_DIM, HID);

  // chunked delta-rule scan
  phaseA_kernel<<<dim3(NVH, NCH), 256, 0, stream>>>(kn, vcb, glb, beta, Wbb, UbT, Gbuf);
  phaseB_kernel<<<2*NVH, 256, 0, stream>>>(qn, kn, Wbb, UbT, Gbuf, Db, obuf);
  phaseC_kernel<<<dim3(NVH, NCH), 256, 0, stream>>>(qn, kn, Gbuf, Db, obuf);

  norm_kernel<<<dim3(S_LEN, NVH), 128, 0, stream>>>(obuf, gate, w_norm, ogb);

  cast_f2b<<<(HID*VAL_DIM)/NC, 256, 0, stream>>>(Wo, wb, HID*VAL_DIM);
  gemm_bf16_bt<<<dim3(HID/128, S_LEN/128), 256, 0, stream>>>(ogb, wb, out, S_LEN, HID, VAL_DIM);
}